// Round 1
// baseline (183.501 us; speedup 1.0000x reference)
//
#include <hip/hip_runtime.h>

#define SQRT2F 1.41421356237309515f

enum : int {
  S_OFF    = 0,          // s[b][i]            : 256
  DM_OFF   = 256,        // demod[b][o]        : 256
  BC_OFF   = 512,        // bc[o]              : 64
  WC_OFF   = 1024,       // Wc[66][64]         : 4224
  FEAT_OFF = 8192,       // feat[b][c][4096]   : 1048576
  G_OFF    = FEAT_OFF + 1048576,  // G[b][4096][64] : 1048576
  WS_FLOATS = G_OFF + 1048576
};

__device__ __align__(16) float WS[WS_FLOATS];

// ---------------------------------------------------------------------------
// prep: per-b modulation s, demod, and bc = b1 @ w2 + b2. grid = 4 blocks.
// ---------------------------------------------------------------------------
__global__ __launch_bounds__(256) void prep_kernel(
    const float* __restrict__ scale1, const float* __restrict__ mod_w,
    const float* __restrict__ mod_b,  const float* __restrict__ conv_w,
    const float* __restrict__ b1,     const float* __restrict__ w2,
    const float* __restrict__ b2) {
  const int b = blockIdx.x;
  const int t = threadIdx.x;
  const int i = t >> 2, qq = t & 3;   // 4 threads per output
  __shared__ float part[256];
  __shared__ float s_sh[64];

  // ---- s[b][i] = scale1[b] . mod_w[i] + mod_b[i]
  {
    const float* sv = scale1 + b * 512 + qq * 128;
    const float* mw = mod_w + i * 512 + qq * 128;
    float p = 0.f;
    for (int k = 0; k < 128; ++k) p += sv[k] * mw[k];
    part[t] = p;
  }
  __syncthreads();
  if (qq == 0) {
    float sval = part[t] + part[t + 1] + part[t + 2] + part[t + 3] + mod_b[i];
    s_sh[i] = sval;
    WS[S_OFF + b * 64 + i] = sval;
  }
  __syncthreads();

  // ---- demod[b][o] = rsqrt( sum_i s[b,i]^2 * sum_tap conv_w[o,i,tap]^2 + 1e-8 )
  {
    const int o = i;
    const float* cw = conv_w + o * 576 + qq * 144;  // 16 in-channels x 9 taps
    float d = 0.f;
    for (int ii = 0; ii < 16; ++ii) {
      float ss = s_sh[qq * 16 + ii];
      float wsq = 0.f;
      #pragma unroll
      for (int k = 0; k < 9; ++k) { float w = cw[ii * 9 + k]; wsq += w * w; }
      d += ss * ss * wsq;
    }
    part[t] = d;
  }
  __syncthreads();
  if (qq == 0)
    WS[DM_OFF + b * 64 + i] =
        rsqrtf(part[t] + part[t + 1] + part[t + 2] + part[t + 3] + 1e-8f);
  __syncthreads();

  // ---- bc[o] = b1 . w2[:,o] + b2[o]  (all 4 blocks write identical values)
  {
    const int o = i;
    const int kb = qq * 64;
    float a = 0.f;
    for (int k = 0; k < 64; ++k) a += b1[kb + k] * w2[(kb + k) * 64 + o];
    part[t] = a;
  }
  __syncthreads();
  if (qq == 0)
    WS[BC_OFF + i] = part[t] + part[t + 1] + part[t + 2] + part[t + 3] + b2[i];
}

// ---------------------------------------------------------------------------
// Wc = w1 @ w2  ([66,256]@[256,64]). grid = 17 blocks x 256.
// ---------------------------------------------------------------------------
__global__ __launch_bounds__(256) void wc_kernel(
    const float* __restrict__ w1, const float* __restrict__ w2) {
  const int idx = blockIdx.x * 256 + threadIdx.x;
  if (idx >= 66 * 64) return;
  const int c = idx >> 6, o = idx & 63;
  const float* r1 = w1 + c * 256;
  float acc = 0.f;
  for (int k = 0; k < 256; ++k) acc += r1[k] * w2[k * 64 + o];
  WS[WC_OFF + idx] = acc;
}

// ---------------------------------------------------------------------------
// Modulated 3x3 conv + demod + instance-norm + affine + fused leaky relu.
// One block per (b, o): 4 waves x 64 lanes; lane = column, wave = 16-row strip.
// ---------------------------------------------------------------------------
__global__ __launch_bounds__(256) void conv_kernel(
    const float* __restrict__ x,      const float* __restrict__ conv_w,
    const float* __restrict__ scale2, const float* __restrict__ shiftp,
    const float* __restrict__ act_b) {
  const int b = blockIdx.x >> 6;
  const int o = blockIdx.x & 63;
  const int t = threadIdx.x;
  __shared__ float wloc[576];
  __shared__ float rs1[4], rs2[4];

  for (int idx = t; idx < 576; idx += 256)
    wloc[idx] = conv_w[o * 576 + idx] * WS[S_OFF + b * 64 + idx / 9];
  __syncthreads();

  const int wave = t >> 6, lane = t & 63;
  const int h0 = wave * 16;
  const int col = lane;
  float acc[16];
  #pragma unroll
  for (int k = 0; k < 16; ++k) acc[k] = 0.f;

  for (int i = 0; i < 64; ++i) {
    const float* xi = x + ((b * 64 + i) << 12);
    const float* wv = wloc + i * 9;
    const float w00 = wv[0], w01 = wv[1], w02 = wv[2];
    const float w10 = wv[3], w11 = wv[4], w12 = wv[5];
    const float w20 = wv[6], w21 = wv[7], w22 = wv[8];
    float l0, c0, r0, l1, c1, r1;
    if (h0 == 0) { l0 = c0 = r0 = 0.f; }
    else {
      const float* row = xi + (h0 - 1) * 64;
      c0 = row[col]; l0 = col ? row[col - 1] : 0.f; r0 = (col < 63) ? row[col + 1] : 0.f;
    }
    {
      const float* row = xi + h0 * 64;
      c1 = row[col]; l1 = col ? row[col - 1] : 0.f; r1 = (col < 63) ? row[col + 1] : 0.f;
    }
    #pragma unroll
    for (int k = 0; k < 16; ++k) {
      float l2, c2, r2;
      const int r = h0 + k + 1;
      if (r > 63) { l2 = c2 = r2 = 0.f; }
      else {
        const float* row = xi + r * 64;
        c2 = row[col]; l2 = col ? row[col - 1] : 0.f; r2 = (col < 63) ? row[col + 1] : 0.f;
      }
      acc[k] += w00 * l0 + w01 * c0 + w02 * r0
              + w10 * l1 + w11 * c1 + w12 * r1
              + w20 * l2 + w21 * c2 + w22 * r2;
      l0 = l1; c0 = c1; r0 = r1;
      l1 = l2; c1 = c2; r1 = r2;
    }
  }

  const float dm = WS[DM_OFF + b * 64 + o];
  float s1 = 0.f, s2 = 0.f;
  #pragma unroll
  for (int k = 0; k < 16; ++k) {
    float v = acc[k] * dm; acc[k] = v;
    s1 += v; s2 += v * v;
  }
  #pragma unroll
  for (int off = 32; off; off >>= 1) {
    s1 += __shfl_down(s1, off);
    s2 += __shfl_down(s2, off);
  }
  if (lane == 0) { rs1[wave] = s1; rs2[wave] = s2; }
  __syncthreads();
  const float S1 = rs1[0] + rs1[1] + rs1[2] + rs1[3];
  const float S2 = rs2[0] + rs2[1] + rs2[2] + rs2[3];
  const float mu = S1 * (1.f / 4096.f);
  const float var = S2 * (1.f / 4096.f) - mu * mu;
  const float rstd = rsqrtf(var + 1e-5f);
  const float a2 = scale2[b * 64 + o], sh = shiftp[b * 64 + o], ab = act_b[o];
  float* fout = WS + FEAT_OFF + ((b * 64 + o) << 12);
  #pragma unroll
  for (int k = 0; k < 16; ++k) {
    float v = (acc[k] - mu) * rstd;
    v = v * a2 + sh + ab;
    v = (v > 0.f ? v : 0.2f * v) * SQRT2F;
    fout[(h0 + k) * 64 + col] = v;
  }
}

// ---------------------------------------------------------------------------
// G[b, cell, o] = feat[b, :, cell] . Wc[:64, o] + bc[o].
// Wave: lane = o, 16 cells per wave. grid = 256 blocks x 256.
// ---------------------------------------------------------------------------
__global__ __launch_bounds__(256) void g_kernel() {
  const int t = threadIdx.x;
  const int wave = t >> 6, lane = t & 63;
  const int base = blockIdx.x * 64;        // global cell index (b*4096 + p)
  const int b = base >> 12;
  const int p0 = (base & 4095) + wave * 16;
  const float* Wc = WS + WC_OFF;
  float acc[16];
  const float bcv = WS[BC_OFF + lane];
  #pragma unroll
  for (int k = 0; k < 16; ++k) acc[k] = bcv;
  const float* featb = WS + FEAT_OFF + ((b * 64) << 12) + p0;
  for (int c = 0; c < 64; ++c) {
    const float w = Wc[c * 64 + lane];
    const float* fb = featb + (c << 12);
    #pragma unroll
    for (int k = 0; k < 16; ++k) acc[k] += fb[k] * w;
  }
  float* g = WS + G_OFF + ((b * 4096 + p0) << 6) + lane;
  #pragma unroll
  for (int k = 0; k < 16; ++k) g[k << 6] = acc[k];
}

// ---------------------------------------------------------------------------
// Output: per query, 4 nearest-cell gathers + affine in rel coords,
// local-ensemble weighting (diagonal-swapped areas). 4 threads per query.
// ---------------------------------------------------------------------------
__global__ __launch_bounds__(256) void out_kernel(float* __restrict__ out) {
  const int t = threadIdx.x;
  const int pl = t >> 2, sub = t & 3;
  const int gq = blockIdx.x * 64 + pl;     // b*65536 + q
  const int b = gq >> 16;
  const int q = gq & 65535;
  const int oy = q >> 8, ox = q & 255;

  const float cy0 = -1.f + (2.f * oy + 1.f) * (1.f / 256.f);
  const float cx0 = -1.f + (2.f * ox + 1.f) * (1.f / 256.f);
  const float lo = -1.f + 1e-6f, hi = 1.f - 1e-6f;

  int cell[4];
  float area[4], rely[4], relx[4];
  int j = 0;
  #pragma unroll
  for (int vx = -1; vx <= 1; vx += 2) {
    #pragma unroll
    for (int vy = -1; vy <= 1; vy += 2) {
      float cy = cy0 + (float)vx * (1.f / 64.f) + 1e-6f;
      cy = fminf(fmaxf(cy, lo), hi);
      float cx = cx0 + (float)vy * (1.f / 64.f) + 1e-6f;
      cx = fminf(fmaxf(cx, lo), hi);
      const float fy = floorf((cy + 1.f) * 0.5f * 64.f);
      const float fx = floorf((cx + 1.f) * 0.5f * 64.f);
      const int iy = (int)fminf(fmaxf(fy, 0.f), 63.f);
      const int ix = (int)fminf(fmaxf(fx, 0.f), 63.f);
      const float qy = -1.f + (2.f * iy + 1.f) * (1.f / 64.f);
      const float qx = -1.f + (2.f * ix + 1.f) * (1.f / 64.f);
      const float ry_ = (cy0 - qy) * 64.f;
      const float rx_ = (cx0 - qx) * 64.f;
      cell[j] = iy * 64 + ix;
      rely[j] = ry_; relx[j] = rx_;
      area[j] = fabsf(ry_ * rx_) + 1e-9f;
      ++j;
    }
  }
  const float tot = area[0] + area[1] + area[2] + area[3];
  float wgt[4];
  #pragma unroll
  for (int k = 0; k < 4; ++k) wgt[k] = area[3 - k] / tot;   // diagonal swap
  const float swy = wgt[0] * rely[0] + wgt[1] * rely[1] + wgt[2] * rely[2] + wgt[3] * rely[3];
  const float swx = wgt[0] * relx[0] + wgt[1] * relx[1] + wgt[2] * relx[2] + wgt[3] * relx[3];

  const int chb = sub * 16;
  const float4* W64 = (const float4*)(WS + WC_OFF + 64 * 64 + chb);
  const float4* W65 = (const float4*)(WS + WC_OFF + 65 * 64 + chb);
  float4 r[4];
  #pragma unroll
  for (int k = 0; k < 4; ++k) {
    const float4 a = W64[k], bv = W65[k];
    r[k].x = swy * a.x + swx * bv.x;
    r[k].y = swy * a.y + swx * bv.y;
    r[k].z = swy * a.z + swx * bv.z;
    r[k].w = swy * a.w + swx * bv.w;
  }
  #pragma unroll
  for (int jj = 0; jj < 4; ++jj) {
    const float4* gp = (const float4*)(WS + G_OFF + ((b * 4096 + cell[jj]) << 6) + chb);
    const float w = wgt[jj];
    #pragma unroll
    for (int k = 0; k < 4; ++k) {
      const float4 gv = gp[k];
      r[k].x += w * gv.x; r[k].y += w * gv.y;
      r[k].z += w * gv.z; r[k].w += w * gv.w;
    }
  }
  float4* op = (float4*)(out + ((size_t)gq << 6) + chb);
  #pragma unroll
  for (int k = 0; k < 4; ++k) op[k] = r[k];
}

// ---------------------------------------------------------------------------
extern "C" void kernel_launch(void* const* d_in, const int* in_sizes, int n_in,
                              void* d_out, int out_size, void* d_ws, size_t ws_size,
                              hipStream_t stream) {
  (void)in_sizes; (void)n_in; (void)out_size; (void)d_ws; (void)ws_size;
  const float* x      = (const float*)d_in[0];
  const float* scale1 = (const float*)d_in[1];
  const float* scale2 = (const float*)d_in[2];
  const float* shiftp = (const float*)d_in[3];
  const float* mod_w  = (const float*)d_in[4];
  const float* mod_b  = (const float*)d_in[5];
  const float* conv_w = (const float*)d_in[6];
  const float* act_b  = (const float*)d_in[7];
  const float* w1     = (const float*)d_in[8];
  const float* b1     = (const float*)d_in[9];
  const float* w2     = (const float*)d_in[10];
  const float* b2     = (const float*)d_in[11];
  float* out = (float*)d_out;

  hipLaunchKernelGGL(prep_kernel, dim3(4), dim3(256), 0, stream,
                     scale1, mod_w, mod_b, conv_w, b1, w2, b2);
  hipLaunchKernelGGL(wc_kernel, dim3(17), dim3(256), 0, stream, w1, w2);
  hipLaunchKernelGGL(conv_kernel, dim3(256), dim3(256), 0, stream,
                     x, conv_w, scale2, shiftp, act_b);
  hipLaunchKernelGGL(g_kernel, dim3(256), dim3(256), 0, stream);
  hipLaunchKernelGGL(out_kernel, dim3(4096), dim3(256), 0, stream, out);
}

// Round 2
// 125.085 us; speedup vs baseline: 1.4670x; 1.4670x over previous
//
#include <hip/hip_runtime.h>

#define SQRT2F 1.41421356237309515f

enum : int {
  S_OFF    = 0,          // s[b][i]            : 256
  DM_OFF   = 256,        // demod[b][o]        : 256
  BC_OFF   = 512,        // bc[o]              : 64
  WC_OFF   = 1024,       // Wc[66][64]         : 4224
  FEAT_OFF = 8192,       // feat[b][c][4096]   : 1048576
  G_OFF    = FEAT_OFF + 1048576,  // G[b][4096][64] : 1048576
  WS_FLOATS = G_OFF + 1048576
};

__device__ __align__(16) float WS[WS_FLOATS];

// ---------------------------------------------------------------------------
// prep: per-b modulation s, demod, and bc = b1 @ w2 + b2. grid = 4 blocks.
// ---------------------------------------------------------------------------
__global__ __launch_bounds__(256) void prep_kernel(
    const float* __restrict__ scale1, const float* __restrict__ mod_w,
    const float* __restrict__ mod_b,  const float* __restrict__ conv_w,
    const float* __restrict__ b1,     const float* __restrict__ w2,
    const float* __restrict__ b2) {
  const int b = blockIdx.x;
  const int t = threadIdx.x;
  const int i = t >> 2, qq = t & 3;   // 4 threads per output
  __shared__ float part[256];
  __shared__ float s_sh[64];

  // ---- s[b][i] = scale1[b] . mod_w[i] + mod_b[i]
  {
    const float* sv = scale1 + b * 512 + qq * 128;
    const float* mw = mod_w + i * 512 + qq * 128;
    float p = 0.f;
    for (int k = 0; k < 128; ++k) p += sv[k] * mw[k];
    part[t] = p;
  }
  __syncthreads();
  if (qq == 0) {
    float sval = part[t] + part[t + 1] + part[t + 2] + part[t + 3] + mod_b[i];
    s_sh[i] = sval;
    WS[S_OFF + b * 64 + i] = sval;
  }
  __syncthreads();

  // ---- demod[b][o] = rsqrt( sum_i s[b,i]^2 * sum_tap conv_w[o,i,tap]^2 + 1e-8 )
  {
    const int o = i;
    const float* cw = conv_w + o * 576 + qq * 144;  // 16 in-channels x 9 taps
    float d = 0.f;
    for (int ii = 0; ii < 16; ++ii) {
      float ss = s_sh[qq * 16 + ii];
      float wsq = 0.f;
      #pragma unroll
      for (int k = 0; k < 9; ++k) { float w = cw[ii * 9 + k]; wsq += w * w; }
      d += ss * ss * wsq;
    }
    part[t] = d;
  }
  __syncthreads();
  if (qq == 0)
    WS[DM_OFF + b * 64 + i] =
        rsqrtf(part[t] + part[t + 1] + part[t + 2] + part[t + 3] + 1e-8f);
  __syncthreads();

  // ---- bc[o] = b1 . w2[:,o] + b2[o]  (all 4 blocks write identical values)
  {
    const int o = i;
    const int kb = qq * 64;
    float a = 0.f;
    for (int k = 0; k < 64; ++k) a += b1[kb + k] * w2[(kb + k) * 64 + o];
    part[t] = a;
  }
  __syncthreads();
  if (qq == 0)
    WS[BC_OFF + i] = part[t] + part[t + 1] + part[t + 2] + part[t + 3] + b2[i];
}

// ---------------------------------------------------------------------------
// Wc = w1 @ w2  ([66,256]@[256,64]). grid = 17 blocks x 256.
// ---------------------------------------------------------------------------
__global__ __launch_bounds__(256) void wc_kernel(
    const float* __restrict__ w1, const float* __restrict__ w2) {
  const int idx = blockIdx.x * 256 + threadIdx.x;
  if (idx >= 66 * 64) return;
  const int c = idx >> 6, o = idx & 63;
  const float* r1 = w1 + c * 256;
  float acc = 0.f;
  for (int k = 0; k < 256; ++k) acc += r1[k] * w2[k * 64 + o];
  WS[WC_OFF + idx] = acc;
}

// ---------------------------------------------------------------------------
// Modulated 3x3 conv + demod + instance-norm + affine + fused leaky relu.
// One block per (b, o): 16 waves x 64 lanes; lane = column, wave = 4-row strip.
// 1024 threads -> 16 waves/block, 4 waves/SIMD (vs 1 before).
// ---------------------------------------------------------------------------
__global__ __launch_bounds__(1024) void conv_kernel(
    const float* __restrict__ x,      const float* __restrict__ conv_w,
    const float* __restrict__ scale2, const float* __restrict__ shiftp,
    const float* __restrict__ act_b) {
  const int b = blockIdx.x >> 6;
  const int o = blockIdx.x & 63;
  const int t = threadIdx.x;
  __shared__ float wloc[576];
  __shared__ float rs1[16], rs2[16];

  for (int idx = t; idx < 576; idx += 1024)
    wloc[idx] = conv_w[o * 576 + idx] * WS[S_OFF + b * 64 + idx / 9];
  __syncthreads();

  const int wave = t >> 6, lane = t & 63;
  const int h0 = wave * 4;
  const int col = lane;
  float acc[4] = {0.f, 0.f, 0.f, 0.f};

  for (int i = 0; i < 64; ++i) {
    const float* xi = x + ((b * 64 + i) << 12);
    const float* wv = wloc + i * 9;
    const float w00 = wv[0], w01 = wv[1], w02 = wv[2];
    const float w10 = wv[3], w11 = wv[4], w12 = wv[5];
    const float w20 = wv[6], w21 = wv[7], w22 = wv[8];
    float l0, c0, r0, l1, c1, r1;
    if (h0 == 0) { l0 = c0 = r0 = 0.f; }
    else {
      const float* row = xi + (h0 - 1) * 64;
      c0 = row[col]; l0 = col ? row[col - 1] : 0.f; r0 = (col < 63) ? row[col + 1] : 0.f;
    }
    {
      const float* row = xi + h0 * 64;
      c1 = row[col]; l1 = col ? row[col - 1] : 0.f; r1 = (col < 63) ? row[col + 1] : 0.f;
    }
    #pragma unroll
    for (int k = 0; k < 4; ++k) {
      float l2, c2, r2;
      const int r = h0 + k + 1;
      if (r > 63) { l2 = c2 = r2 = 0.f; }
      else {
        const float* row = xi + r * 64;
        c2 = row[col]; l2 = col ? row[col - 1] : 0.f; r2 = (col < 63) ? row[col + 1] : 0.f;
      }
      acc[k] += w00 * l0 + w01 * c0 + w02 * r0
              + w10 * l1 + w11 * c1 + w12 * r1
              + w20 * l2 + w21 * c2 + w22 * r2;
      l0 = l1; c0 = c1; r0 = r1;
      l1 = l2; c1 = c2; r1 = r2;
    }
  }

  const float dm = WS[DM_OFF + b * 64 + o];
  float s1 = 0.f, s2 = 0.f;
  #pragma unroll
  for (int k = 0; k < 4; ++k) {
    float v = acc[k] * dm; acc[k] = v;
    s1 += v; s2 += v * v;
  }
  #pragma unroll
  for (int off = 32; off; off >>= 1) {
    s1 += __shfl_down(s1, off);
    s2 += __shfl_down(s2, off);
  }
  if (lane == 0) { rs1[wave] = s1; rs2[wave] = s2; }
  __syncthreads();
  float S1 = 0.f, S2 = 0.f;
  #pragma unroll
  for (int w = 0; w < 16; ++w) { S1 += rs1[w]; S2 += rs2[w]; }
  const float mu = S1 * (1.f / 4096.f);
  const float var = S2 * (1.f / 4096.f) - mu * mu;
  const float rstd = rsqrtf(var + 1e-5f);
  const float a2 = scale2[b * 64 + o], sh = shiftp[b * 64 + o], ab = act_b[o];
  float* fout = WS + FEAT_OFF + ((b * 64 + o) << 12);
  #pragma unroll
  for (int k = 0; k < 4; ++k) {
    float v = (acc[k] - mu) * rstd;
    v = v * a2 + sh + ab;
    v = (v > 0.f ? v : 0.2f * v) * SQRT2F;
    fout[(h0 + k) * 64 + col] = v;
  }
}

// ---------------------------------------------------------------------------
// G[b, cell, o] = feat[b, :, cell] . Wc[:64, o] + bc[o].
// Wave: lane = o, 16 cells per wave. grid = 256 blocks x 256.
// ---------------------------------------------------------------------------
__global__ __launch_bounds__(256) void g_kernel() {
  const int t = threadIdx.x;
  const int wave = t >> 6, lane = t & 63;
  const int base = blockIdx.x * 64;        // global cell index (b*4096 + p)
  const int b = base >> 12;
  const int p0 = (base & 4095) + wave * 16;
  const float* Wc = WS + WC_OFF;
  float acc[16];
  const float bcv = WS[BC_OFF + lane];
  #pragma unroll
  for (int k = 0; k < 16; ++k) acc[k] = bcv;
  const float* featb = WS + FEAT_OFF + ((b * 64) << 12) + p0;
  for (int c = 0; c < 64; ++c) {
    const float w = Wc[c * 64 + lane];
    const float* fb = featb + (c << 12);
    #pragma unroll
    for (int k = 0; k < 16; ++k) acc[k] += fb[k] * w;
  }
  float* g = WS + G_OFF + ((b * 4096 + p0) << 6) + lane;
  #pragma unroll
  for (int k = 0; k < 16; ++k) g[k << 6] = acc[k];
}

// ---------------------------------------------------------------------------
// Output: per query, 4 nearest-cell gathers + affine in rel coords,
// local-ensemble weighting (diagonal-swapped areas). 4 threads per query.
// ---------------------------------------------------------------------------
__global__ __launch_bounds__(256) void out_kernel(float* __restrict__ out) {
  const int t = threadIdx.x;
  const int pl = t >> 2, sub = t & 3;
  const int gq = blockIdx.x * 64 + pl;     // b*65536 + q
  const int b = gq >> 16;
  const int q = gq & 65535;
  const int oy = q >> 8, ox = q & 255;

  const float cy0 = -1.f + (2.f * oy + 1.f) * (1.f / 256.f);
  const float cx0 = -1.f + (2.f * ox + 1.f) * (1.f / 256.f);
  const float lo = -1.f + 1e-6f, hi = 1.f - 1e-6f;

  int cell[4];
  float area[4], rely[4], relx[4];
  int j = 0;
  #pragma unroll
  for (int vx = -1; vx <= 1; vx += 2) {
    #pragma unroll
    for (int vy = -1; vy <= 1; vy += 2) {
      float cy = cy0 + (float)vx * (1.f / 64.f) + 1e-6f;
      cy = fminf(fmaxf(cy, lo), hi);
      float cx = cx0 + (float)vy * (1.f / 64.f) + 1e-6f;
      cx = fminf(fmaxf(cx, lo), hi);
      const float fy = floorf((cy + 1.f) * 0.5f * 64.f);
      const float fx = floorf((cx + 1.f) * 0.5f * 64.f);
      const int iy = (int)fminf(fmaxf(fy, 0.f), 63.f);
      const int ix = (int)fminf(fmaxf(fx, 0.f), 63.f);
      const float qy = -1.f + (2.f * iy + 1.f) * (1.f / 64.f);
      const float qx = -1.f + (2.f * ix + 1.f) * (1.f / 64.f);
      const float ry_ = (cy0 - qy) * 64.f;
      const float rx_ = (cx0 - qx) * 64.f;
      cell[j] = iy * 64 + ix;
      rely[j] = ry_; relx[j] = rx_;
      area[j] = fabsf(ry_ * rx_) + 1e-9f;
      ++j;
    }
  }
  const float tot = area[0] + area[1] + area[2] + area[3];
  float wgt[4];
  #pragma unroll
  for (int k = 0; k < 4; ++k) wgt[k] = area[3 - k] / tot;   // diagonal swap
  const float swy = wgt[0] * rely[0] + wgt[1] * rely[1] + wgt[2] * rely[2] + wgt[3] * rely[3];
  const float swx = wgt[0] * relx[0] + wgt[1] * relx[1] + wgt[2] * relx[2] + wgt[3] * relx[3];

  const int chb = sub * 16;
  const float4* W64 = (const float4*)(WS + WC_OFF + 64 * 64 + chb);
  const float4* W65 = (const float4*)(WS + WC_OFF + 65 * 64 + chb);
  float4 r[4];
  #pragma unroll
  for (int k = 0; k < 4; ++k) {
    const float4 a = W64[k], bv = W65[k];
    r[k].x = swy * a.x + swx * bv.x;
    r[k].y = swy * a.y + swx * bv.y;
    r[k].z = swy * a.z + swx * bv.z;
    r[k].w = swy * a.w + swx * bv.w;
  }
  #pragma unroll
  for (int jj = 0; jj < 4; ++jj) {
    const float4* gp = (const float4*)(WS + G_OFF + ((b * 4096 + cell[jj]) << 6) + chb);
    const float w = wgt[jj];
    #pragma unroll
    for (int k = 0; k < 4; ++k) {
      const float4 gv = gp[k];
      r[k].x += w * gv.x; r[k].y += w * gv.y;
      r[k].z += w * gv.z; r[k].w += w * gv.w;
    }
  }
  float4* op = (float4*)(out + ((size_t)gq << 6) + chb);
  #pragma unroll
  for (int k = 0; k < 4; ++k) op[k] = r[k];
}

// ---------------------------------------------------------------------------
extern "C" void kernel_launch(void* const* d_in, const int* in_sizes, int n_in,
                              void* d_out, int out_size, void* d_ws, size_t ws_size,
                              hipStream_t stream) {
  (void)in_sizes; (void)n_in; (void)out_size; (void)d_ws; (void)ws_size;
  const float* x      = (const float*)d_in[0];
  const float* scale1 = (const float*)d_in[1];
  const float* scale2 = (const float*)d_in[2];
  const float* shiftp = (const float*)d_in[3];
  const float* mod_w  = (const float*)d_in[4];
  const float* mod_b  = (const float*)d_in[5];
  const float* conv_w = (const float*)d_in[6];
  const float* act_b  = (const float*)d_in[7];
  const float* w1     = (const float*)d_in[8];
  const float* b1     = (const float*)d_in[9];
  const float* w2     = (const float*)d_in[10];
  const float* b2     = (const float*)d_in[11];
  float* out = (float*)d_out;

  hipLaunchKernelGGL(prep_kernel, dim3(4), dim3(256), 0, stream,
                     scale1, mod_w, mod_b, conv_w, b1, w2, b2);
  hipLaunchKernelGGL(wc_kernel, dim3(17), dim3(256), 0, stream, w1, w2);
  hipLaunchKernelGGL(conv_kernel, dim3(256), dim3(1024), 0, stream,
                     x, conv_w, scale2, shiftp, act_b);
  hipLaunchKernelGGL(g_kernel, dim3(256), dim3(256), 0, stream);
  hipLaunchKernelGGL(out_kernel, dim3(4096), dim3(256), 0, stream, out);
}

// Round 3
// 109.139 us; speedup vs baseline: 1.6814x; 1.1461x over previous
//
#include <hip/hip_runtime.h>

#define SQRT2F 1.41421356237309515f

typedef __attribute__((ext_vector_type(8))) short bf16x8;
typedef __attribute__((ext_vector_type(4))) float f32x4;

enum : int {
  S_OFF    = 0,          // s[b][i]                 : 256
  DM_OFF   = 256,        // demod[b][o]             : 256
  BC_OFF   = 512,        // bc[o]                   : 64
  WC_OFF   = 1024,       // Wc[66][64]              : 4224 (ends 5248)
  CA_OFF   = 6144,       // A coef [b*64+o]         : 256
  CB_OFF   = 6400,       // B coef [b*64+o]         : 256
  P_OFF    = 8192,       // partials[b][32][64][2]  : 16384 (ends 24576)
  WMOD_OFF = 24576,      // bf16 Wmod[b][o][9][64]  : 147456 ushort = 73728 fl
  Y_OFF    = 131072,     // y[b][c][4096] raw conv  : 1048576
  FEAT_OFF = Y_OFF + 1048576,
  G_OFF    = FEAT_OFF + 1048576,
  WS_FLOATS = G_OFF + 1048576
};

__device__ __align__(16) float WS[WS_FLOATS];

__device__ __forceinline__ unsigned short f2bf(float v) {
  unsigned int u = __float_as_uint(v);
  u += 0x7fffu + ((u >> 16) & 1u);
  return (unsigned short)(u >> 16);
}

// ---------------------------------------------------------------------------
// prep: per-b modulation s, demod, bc = b1@w2+b2, and bf16 Wmod[b][o][tap][ich]
// ---------------------------------------------------------------------------
__global__ __launch_bounds__(256) void prep_kernel(
    const float* __restrict__ scale1, const float* __restrict__ mod_w,
    const float* __restrict__ mod_b,  const float* __restrict__ conv_w,
    const float* __restrict__ b1,     const float* __restrict__ w2,
    const float* __restrict__ b2) {
  const int b = blockIdx.x;
  const int t = threadIdx.x;
  const int i = t >> 2, qq = t & 3;
  __shared__ float part[256];
  __shared__ float s_sh[64];

  // ---- s[b][i]
  {
    const float* sv = scale1 + b * 512 + qq * 128;
    const float* mw = mod_w + i * 512 + qq * 128;
    float p = 0.f;
    for (int k = 0; k < 128; ++k) p += sv[k] * mw[k];
    part[t] = p;
  }
  __syncthreads();
  if (qq == 0) {
    float sval = part[t] + part[t + 1] + part[t + 2] + part[t + 3] + mod_b[i];
    s_sh[i] = sval;
    WS[S_OFF + b * 64 + i] = sval;
  }
  __syncthreads();

  // ---- demod[b][o] (f32, identical to reference)
  {
    const int o = i;
    const float* cw = conv_w + o * 576 + qq * 144;
    float d = 0.f;
    for (int ii = 0; ii < 16; ++ii) {
      float ss = s_sh[qq * 16 + ii];
      float wsq = 0.f;
      #pragma unroll
      for (int k = 0; k < 9; ++k) { float w = cw[ii * 9 + k]; wsq += w * w; }
      d += ss * ss * wsq;
    }
    part[t] = d;
  }
  __syncthreads();
  if (qq == 0)
    WS[DM_OFF + b * 64 + i] =
        rsqrtf(part[t] + part[t + 1] + part[t + 2] + part[t + 3] + 1e-8f);
  __syncthreads();

  // ---- bc[o]
  {
    const int o = i;
    const int kb = qq * 64;
    float a = 0.f;
    for (int k = 0; k < 64; ++k) a += b1[kb + k] * w2[(kb + k) * 64 + o];
    part[t] = a;
  }
  __syncthreads();
  if (qq == 0)
    WS[BC_OFF + i] = part[t] + part[t + 1] + part[t + 2] + part[t + 3] + b2[i];

  // ---- Wmod bf16: [(b*64+o)*9 + tap]*64 + ich = s[ich] * conv_w[o][ich][tap]
  unsigned short* wm = (unsigned short*)(WS + WMOD_OFF);
  for (int idx = t; idx < 64 * 576; idx += 256) {
    const int o = idx / 576;
    const int rem = idx - o * 576;
    const int tap = rem >> 6, ich = rem & 63;
    wm[(size_t)b * 36864 + idx] = f2bf(conv_w[o * 576 + ich * 9 + tap] * s_sh[ich]);
  }
}

// ---------------------------------------------------------------------------
// Wc = w1 @ w2
// ---------------------------------------------------------------------------
__global__ __launch_bounds__(256) void wc_kernel(
    const float* __restrict__ w1, const float* __restrict__ w2) {
  const int idx = blockIdx.x * 256 + threadIdx.x;
  if (idx >= 66 * 64) return;
  const int c = idx >> 6, o = idx & 63;
  const float* r1 = w1 + c * 256;
  float acc = 0.f;
  for (int k = 0; k < 256; ++k) acc += r1[k] * w2[k * 64 + o];
  WS[WC_OFF + idx] = acc;
}

// ---------------------------------------------------------------------------
// MFMA conv: block = (b, row-pair rg). y_raw[b][o][px] + per-block partials.
// LDS: Xl = bf16 x-tile [4 rows][66 cols][64 ich], XOR-swizzled 16B groups.
//      Wl = bf16 weight slice [64 o][3 taps][64 ich], XOR-swizzled.
// Wave w: 64o x 32px (4m x 2n register tile).
// ---------------------------------------------------------------------------
__global__ __launch_bounds__(256) void conv_kernel(const float* __restrict__ x) {
  const int b = blockIdx.x >> 5;
  const int rg = blockIdx.x & 31;          // rows 2rg, 2rg+1
  const int t = threadIdx.x;
  const int w = t >> 6, lane = t & 63;
  const int l15 = lane & 15, l4 = lane >> 4;

  __shared__ __align__(16) unsigned short Xl[4 * 66 * 64];   // 33792 B
  __shared__ __align__(16) unsigned short Wl[64 * 24 * 8];   // 24576 B

  // ---- zero-init X (covers SAME-padding cols/rows)
  {
    int4* Xz = (int4*)Xl;
    int4 z; z.x = z.y = z.z = z.w = 0;
    for (int idx = t; idx < 2112; idx += 256) Xz[idx] = z;
  }
  __syncthreads();

  // ---- stage x rows 2rg-1 .. 2rg+2 as bf16, swizzled
  {
    const int col = t & 63;
    const int tq = t >> 6;                 // 4 tasks per iter
    unsigned int* Xw = (unsigned int*)Xl;
    for (int it = 0; it < 32; ++it) {
      const int task = it * 4 + tq;        // 0..127 = row3*32 + ichpair
      const int row3 = task >> 5;
      const int ich = (task & 31) * 2;
      const int rr = 2 * rg - 1 + row3;
      if (rr >= 0 && rr < 64) {
        const float* xb = x + ((size_t)(b * 64 + ich) << 12) + (rr << 6) + col;
        const float v0 = xb[0];
        const float v1 = xb[4096];
        const unsigned int u = (unsigned int)f2bf(v0) | ((unsigned int)f2bf(v1) << 16);
        const int colp = col + 1;
        const int byte = ((row3 * 66 + colp) << 7) + ((((ich >> 3)) ^ (colp & 7)) << 4) + ((ich & 7) << 1);
        Xw[byte >> 2] = u;
      }
    }
  }

  f32x4 acc[4][2];
  #pragma unroll
  for (int m = 0; m < 4; ++m)
    #pragma unroll
    for (int n = 0; n < 2; ++n) acc[m][n] = (f32x4){0.f, 0.f, 0.f, 0.f};

  const int4* wmg = (const int4*)(WS + WMOD_OFF);
  const bf16x8* Xv = (const bf16x8*)Xl;
  const bf16x8* Wv = (const bf16x8*)Wl;
  int4* Wst = (int4*)Wl;

  for (int dy = 0; dy < 3; ++dy) {
    __syncthreads();                        // done reading previous W slice
    // stage W slice for this dy: taps (dy,0..2)
    for (int i = 0; i < 6; ++i) {
      const int idx = i * 256 + t;          // 0..1535 = o*24 + dx*8 + gg
      const int o = idx / 24;
      const int g = idx - o * 24;
      const int dx = g >> 3, gg = g & 7;
      const int4 v = wmg[((size_t)(b * 64 + o) * 9 + dy * 3 + dx) * 8 + gg];
      Wst[o * 24 + dx * 8 + (gg ^ (o & 7))] = v;
    }
    __syncthreads();

    #pragma unroll
    for (int dx = 0; dx < 3; ++dx) {
      #pragma unroll
      for (int kh = 0; kh < 2; ++kh) {
        const int kg = kh * 4 + l4;         // 16B-group index in ich (0..7)
        bf16x8 afr[4];
        #pragma unroll
        for (int m = 0; m < 4; ++m) {
          const int o = m * 16 + l15;
          afr[m] = Wv[o * 24 + dx * 8 + (kg ^ (o & 7))];
        }
        bf16x8 bfr[2];
        #pragma unroll
        for (int n = 0; n < 2; ++n) {
          const int pbase = w * 32 + n * 16;
          const int rip = pbase >> 6;
          const int col = (pbase & 63) + l15;
          const int row3 = rip + dy;
          const int colp = col + dx;        // input col-1 .. col+1, padded
          bfr[n] = Xv[((row3 * 66 + colp) << 3) + (kg ^ (colp & 7))];
        }
        #pragma unroll
        for (int m = 0; m < 4; ++m)
          #pragma unroll
          for (int n = 0; n < 2; ++n)
            acc[m][n] = __builtin_amdgcn_mfma_f32_16x16x32_bf16(
                afr[m], bfr[n], acc[m][n], 0, 0, 0);
      }
    }
  }

  // ---- store raw y. D layout: col = lane&15 (px), row(o) = (lane>>4)*4 + j
  #pragma unroll
  for (int m = 0; m < 4; ++m) {
    #pragma unroll
    for (int n = 0; n < 2; ++n) {
      const int pbase = w * 32 + n * 16;
      const int rip = pbase >> 6;
      const int cb = (pbase & 63) + l15;
      #pragma unroll
      for (int j = 0; j < 4; ++j) {
        const int o = m * 16 + l4 * 4 + j;
        WS[Y_OFF + ((size_t)(b * 64 + o) << 12) + ((2 * rg + rip) << 6) + cb] =
            acc[m][n][j];
      }
    }
  }

  // ---- per-block partial sums (deterministic, no atomics)
  __syncthreads();                          // all waves done reading Wl
  float* sred = (float*)Wl;                 // [4 waves][64 o][2]
  {
    #pragma unroll
    for (int m = 0; m < 4; ++m) {
      #pragma unroll
      for (int j = 0; j < 4; ++j) {
        float a0 = acc[m][0][j], a1 = acc[m][1][j];
        float s1 = a0 + a1;
        float s2 = a0 * a0 + a1 * a1;
        #pragma unroll
        for (int off = 1; off < 16; off <<= 1) {
          s1 += __shfl_xor(s1, off);
          s2 += __shfl_xor(s2, off);
        }
        if (l15 == 0) {
          const int o = m * 16 + l4 * 4 + j;
          sred[(w * 64 + o) * 2 + 0] = s1;
          sred[(w * 64 + o) * 2 + 1] = s2;
        }
      }
    }
  }
  __syncthreads();
  if (t < 128) {
    const int o = t >> 1, wh = t & 1;
    float s = sred[o * 2 + wh] + sred[(64 + o) * 2 + wh] +
              sred[(128 + o) * 2 + wh] + sred[(192 + o) * 2 + wh];
    WS[P_OFF + (((size_t)b * 32 + rg) * 64 + o) * 2 + wh] = s;
  }
}

// ---------------------------------------------------------------------------
// stats: fold mean/var/demod/affine into per-(b,c) A,B coefs.
// ---------------------------------------------------------------------------
__global__ __launch_bounds__(256) void stats_kernel(
    const float* __restrict__ scale2, const float* __restrict__ shiftp,
    const float* __restrict__ act_b) {
  const int t = threadIdx.x;                // = b*64 + o
  const int b = t >> 6, o = t & 63;
  float S1 = 0.f, S2 = 0.f;
  const float* p = WS + P_OFF + ((size_t)b * 32) * 128 + o * 2;
  for (int rg = 0; rg < 32; ++rg) { S1 += p[rg * 128]; S2 += p[rg * 128 + 1]; }
  const float mu = S1 * (1.f / 4096.f);
  const float var = S2 * (1.f / 4096.f) - mu * mu;
  const float dm = WS[DM_OFF + t];
  const float rstd = rsqrtf(dm * dm * var + 1e-5f);
  const float a2 = scale2[t];
  const float A = dm * rstd * a2;
  WS[CA_OFF + t] = A;
  WS[CB_OFF + t] = -mu * A + shiftp[t] + act_b[o];
}

// ---------------------------------------------------------------------------
// feat = leakyrelu(y*A + B) * sqrt2   (elementwise, float4)
// ---------------------------------------------------------------------------
__global__ __launch_bounds__(256) void feat_kernel() {
  const int idx = blockIdx.x * 256 + threadIdx.x;   // float4 index
  const int c = idx >> 10;                          // b*64+o
  const float A = WS[CA_OFF + c], B = WS[CB_OFF + c];
  const float4 y = ((const float4*)(WS + Y_OFF))[idx];
  float4 f;
  float u;
  u = y.x * A + B; f.x = (u > 0.f ? u : 0.2f * u) * SQRT2F;
  u = y.y * A + B; f.y = (u > 0.f ? u : 0.2f * u) * SQRT2F;
  u = y.z * A + B; f.z = (u > 0.f ? u : 0.2f * u) * SQRT2F;
  u = y.w * A + B; f.w = (u > 0.f ? u : 0.2f * u) * SQRT2F;
  ((float4*)(WS + FEAT_OFF))[idx] = f;
}

// ---------------------------------------------------------------------------
// G[b, cell, o] = feat[b, :, cell] . Wc[:64, o] + bc[o].
// ---------------------------------------------------------------------------
__global__ __launch_bounds__(256) void g_kernel() {
  const int t = threadIdx.x;
  const int wave = t >> 6, lane = t & 63;
  const int base = blockIdx.x * 64;
  const int b = base >> 12;
  const int p0 = (base & 4095) + wave * 16;
  const float* Wc = WS + WC_OFF;
  float acc[16];
  const float bcv = WS[BC_OFF + lane];
  #pragma unroll
  for (int k = 0; k < 16; ++k) acc[k] = bcv;
  const float* featb = WS + FEAT_OFF + ((size_t)(b * 64) << 12) + p0;
  for (int c = 0; c < 64; ++c) {
    const float w = Wc[c * 64 + lane];
    const float* fb = featb + ((size_t)c << 12);
    #pragma unroll
    for (int k = 0; k < 16; ++k) acc[k] += fb[k] * w;
  }
  float* g = WS + G_OFF + (((size_t)b * 4096 + p0) << 6) + lane;
  #pragma unroll
  for (int k = 0; k < 16; ++k) g[k << 6] = acc[k];
}

// ---------------------------------------------------------------------------
// Output: local-ensemble gather + affine. 4 threads per query.
// ---------------------------------------------------------------------------
__global__ __launch_bounds__(256) void out_kernel(float* __restrict__ out) {
  const int t = threadIdx.x;
  const int pl = t >> 2, sub = t & 3;
  const int gq = blockIdx.x * 64 + pl;
  const int b = gq >> 16;
  const int q = gq & 65535;
  const int oy = q >> 8, ox = q & 255;

  const float cy0 = -1.f + (2.f * oy + 1.f) * (1.f / 256.f);
  const float cx0 = -1.f + (2.f * ox + 1.f) * (1.f / 256.f);
  const float lo = -1.f + 1e-6f, hi = 1.f - 1e-6f;

  int cell[4];
  float area[4], rely[4], relx[4];
  int j = 0;
  #pragma unroll
  for (int vx = -1; vx <= 1; vx += 2) {
    #pragma unroll
    for (int vy = -1; vy <= 1; vy += 2) {
      float cy = cy0 + (float)vx * (1.f / 64.f) + 1e-6f;
      cy = fminf(fmaxf(cy, lo), hi);
      float cx = cx0 + (float)vy * (1.f / 64.f) + 1e-6f;
      cx = fminf(fmaxf(cx, lo), hi);
      const float fy = floorf((cy + 1.f) * 0.5f * 64.f);
      const float fx = floorf((cx + 1.f) * 0.5f * 64.f);
      const int iy = (int)fminf(fmaxf(fy, 0.f), 63.f);
      const int ix = (int)fminf(fmaxf(fx, 0.f), 63.f);
      const float qy = -1.f + (2.f * iy + 1.f) * (1.f / 64.f);
      const float qx = -1.f + (2.f * ix + 1.f) * (1.f / 64.f);
      const float ry_ = (cy0 - qy) * 64.f;
      const float rx_ = (cx0 - qx) * 64.f;
      cell[j] = iy * 64 + ix;
      rely[j] = ry_; relx[j] = rx_;
      area[j] = fabsf(ry_ * rx_) + 1e-9f;
      ++j;
    }
  }
  const float tot = area[0] + area[1] + area[2] + area[3];
  float wgt[4];
  #pragma unroll
  for (int k = 0; k < 4; ++k) wgt[k] = area[3 - k] / tot;
  const float swy = wgt[0] * rely[0] + wgt[1] * rely[1] + wgt[2] * rely[2] + wgt[3] * rely[3];
  const float swx = wgt[0] * relx[0] + wgt[1] * relx[1] + wgt[2] * relx[2] + wgt[3] * relx[3];

  const int chb = sub * 16;
  const float4* W64 = (const float4*)(WS + WC_OFF + 64 * 64 + chb);
  const float4* W65 = (const float4*)(WS + WC_OFF + 65 * 64 + chb);
  float4 r[4];
  #pragma unroll
  for (int k = 0; k < 4; ++k) {
    const float4 a = W64[k], bv = W65[k];
    r[k].x = swy * a.x + swx * bv.x;
    r[k].y = swy * a.y + swx * bv.y;
    r[k].z = swy * a.z + swx * bv.z;
    r[k].w = swy * a.w + swx * bv.w;
  }
  #pragma unroll
  for (int jj = 0; jj < 4; ++jj) {
    const float4* gp = (const float4*)(WS + G_OFF + (((size_t)b * 4096 + cell[jj]) << 6) + chb);
    const float wv = wgt[jj];
    #pragma unroll
    for (int k = 0; k < 4; ++k) {
      const float4 gv = gp[k];
      r[k].x += wv * gv.x; r[k].y += wv * gv.y;
      r[k].z += wv * gv.z; r[k].w += wv * gv.w;
    }
  }
  float4* op = (float4*)(out + ((size_t)gq << 6) + chb);
  #pragma unroll
  for (int k = 0; k < 4; ++k) op[k] = r[k];
}

// ---------------------------------------------------------------------------
extern "C" void kernel_launch(void* const* d_in, const int* in_sizes, int n_in,
                              void* d_out, int out_size, void* d_ws, size_t ws_size,
                              hipStream_t stream) {
  (void)in_sizes; (void)n_in; (void)out_size; (void)d_ws; (void)ws_size;
  const float* x      = (const float*)d_in[0];
  const float* scale1 = (const float*)d_in[1];
  const float* scale2 = (const float*)d_in[2];
  const float* shiftp = (const float*)d_in[3];
  const float* mod_w  = (const float*)d_in[4];
  const float* mod_b  = (const float*)d_in[5];
  const float* conv_w = (const float*)d_in[6];
  const float* act_b  = (const float*)d_in[7];
  const float* w1     = (const float*)d_in[8];
  const float* b1     = (const float*)d_in[9];
  const float* w2     = (const float*)d_in[10];
  const float* b2     = (const float*)d_in[11];
  float* out = (float*)d_out;

  hipLaunchKernelGGL(prep_kernel, dim3(4), dim3(256), 0, stream,
                     scale1, mod_w, mod_b, conv_w, b1, w2, b2);
  hipLaunchKernelGGL(wc_kernel, dim3(17), dim3(256), 0, stream, w1, w2);
  hipLaunchKernelGGL(conv_kernel, dim3(128), dim3(256), 0, stream, x);
  hipLaunchKernelGGL(stats_kernel, dim3(1), dim3(256), 0, stream,
                     scale2, shiftp, act_b);
  hipLaunchKernelGGL(feat_kernel, dim3(1024), dim3(256), 0, stream);
  hipLaunchKernelGGL(g_kernel, dim3(256), dim3(256), 0, stream);
  hipLaunchKernelGGL(out_kernel, dim3(4096), dim3(256), 0, stream, out);
}

// Round 4
// 100.046 us; speedup vs baseline: 1.8342x; 1.0909x over previous
//
#include <hip/hip_runtime.h>

#define SQRT2F 1.41421356237309515f

typedef __attribute__((ext_vector_type(8))) short bf16x8;
typedef __attribute__((ext_vector_type(4))) float f32x4;

enum : int {
  S_OFF    = 0,          // s[b][i]                 : 256
  DM_OFF   = 256,        // demod[b][o]             : 256
  BC_OFF   = 512,        // bc[o]                   : 64
  WC_OFF   = 1024,       // Wc[66][64]              : 4224 (ends 5248)
  P_OFF    = 8192,       // partials[b][32][64][2]  : 16384 (ends 24576)
  WMOD_OFF = 24576,      // bf16 Wmod[b][o][9][64]  : 147456 ushort = 73728 fl
  Y_OFF    = 131072,     // y[b][c][4096] raw conv  : 1048576
  G_OFF    = Y_OFF + 1048576,    // G[b][4096][64]  : 1048576
  WS_FLOATS = G_OFF + 1048576
};

__device__ __align__(16) float WS[WS_FLOATS];

__device__ __forceinline__ unsigned short f2bf(float v) {
  unsigned int u = __float_as_uint(v);
  u += 0x7fffu + ((u >> 16) & 1u);
  return (unsigned short)(u >> 16);
}

// ---------------------------------------------------------------------------
// prepwc: blocks 0-3 = per-b modulation s, demod, bc, bf16 Wmod.
//         blocks 4-20 = Wc = w1 @ w2.
// ---------------------------------------------------------------------------
__global__ __launch_bounds__(256) void prepwc_kernel(
    const float* __restrict__ scale1, const float* __restrict__ mod_w,
    const float* __restrict__ mod_b,  const float* __restrict__ conv_w,
    const float* __restrict__ b1,     const float* __restrict__ w2,
    const float* __restrict__ b2,     const float* __restrict__ w1) {
  const int t = threadIdx.x;

  if (blockIdx.x >= 4) {
    // ---- Wc = w1 @ w2  ([66,256]@[256,64])
    const int idx = (blockIdx.x - 4) * 256 + t;
    if (idx < 66 * 64) {
      const int c = idx >> 6, o = idx & 63;
      const float* r1 = w1 + c * 256;
      float acc = 0.f;
      for (int k = 0; k < 256; ++k) acc += r1[k] * w2[k * 64 + o];
      WS[WC_OFF + idx] = acc;
    }
    return;
  }

  const int b = blockIdx.x;
  const int i = t >> 2, qq = t & 3;
  __shared__ float part[256];
  __shared__ float s_sh[64];

  // ---- s[b][i] = scale1[b] . mod_w[i] + mod_b[i]
  {
    const float* sv = scale1 + b * 512 + qq * 128;
    const float* mw = mod_w + i * 512 + qq * 128;
    float p = 0.f;
    for (int k = 0; k < 128; ++k) p += sv[k] * mw[k];
    part[t] = p;
  }
  __syncthreads();
  if (qq == 0) {
    float sval = part[t] + part[t + 1] + part[t + 2] + part[t + 3] + mod_b[i];
    s_sh[i] = sval;
    WS[S_OFF + b * 64 + i] = sval;
  }
  __syncthreads();

  // ---- demod[b][o] (f32, identical to reference)
  {
    const int o = i;
    const float* cw = conv_w + o * 576 + qq * 144;
    float d = 0.f;
    for (int ii = 0; ii < 16; ++ii) {
      float ss = s_sh[qq * 16 + ii];
      float wsq = 0.f;
      #pragma unroll
      for (int k = 0; k < 9; ++k) { float w = cw[ii * 9 + k]; wsq += w * w; }
      d += ss * ss * wsq;
    }
    part[t] = d;
  }
  __syncthreads();
  if (qq == 0)
    WS[DM_OFF + b * 64 + i] =
        rsqrtf(part[t] + part[t + 1] + part[t + 2] + part[t + 3] + 1e-8f);
  __syncthreads();

  // ---- bc[o] = b1 . w2[:,o] + b2[o]
  {
    const int o = i;
    const int kb = qq * 64;
    float a = 0.f;
    for (int k = 0; k < 64; ++k) a += b1[kb + k] * w2[(kb + k) * 64 + o];
    part[t] = a;
  }
  __syncthreads();
  if (qq == 0)
    WS[BC_OFF + i] = part[t] + part[t + 1] + part[t + 2] + part[t + 3] + b2[i];

  // ---- Wmod bf16 [(b*64+o)*9 + tap]*64 + ich, coalesced READS of conv_w
  unsigned short* wm = (unsigned short*)(WS + WMOD_OFF);
  for (int it = 0; it < 144; ++it) {
    const int ridx = it * 256 + t;            // = o*576 + ich*9 + tap
    const int o = ridx / 576;
    const int rem = ridx - o * 576;
    const int ich = rem / 9;
    const int tap = rem - ich * 9;
    wm[(size_t)b * 36864 + o * 576 + tap * 64 + ich] =
        f2bf(conv_w[ridx] * s_sh[ich]);
  }
}

// ---------------------------------------------------------------------------
// MFMA conv: block = (b, row-pair rg). y_raw[b][o][px] + per-block partials.
// ---------------------------------------------------------------------------
__global__ __launch_bounds__(256) void conv_kernel(const float* __restrict__ x) {
  const int b = blockIdx.x >> 5;
  const int rg = blockIdx.x & 31;          // rows 2rg, 2rg+1
  const int t = threadIdx.x;
  const int w = t >> 6, lane = t & 63;
  const int l15 = lane & 15, l4 = lane >> 4;

  __shared__ __align__(16) unsigned short Xl[4 * 66 * 64];   // 33792 B
  __shared__ __align__(16) unsigned short Wl[64 * 24 * 8];   // 24576 B

  {
    int4* Xz = (int4*)Xl;
    int4 z; z.x = z.y = z.z = z.w = 0;
    for (int idx = t; idx < 2112; idx += 256) Xz[idx] = z;
  }
  __syncthreads();

  {
    const int col = t & 63;
    const int tq = t >> 6;
    unsigned int* Xw = (unsigned int*)Xl;
    for (int it = 0; it < 32; ++it) {
      const int task = it * 4 + tq;
      const int row3 = task >> 5;
      const int ich = (task & 31) * 2;
      const int rr = 2 * rg - 1 + row3;
      if (rr >= 0 && rr < 64) {
        const float* xb = x + ((size_t)(b * 64 + ich) << 12) + (rr << 6) + col;
        const float v0 = xb[0];
        const float v1 = xb[4096];
        const unsigned int u = (unsigned int)f2bf(v0) | ((unsigned int)f2bf(v1) << 16);
        const int colp = col + 1;
        const int byte = ((row3 * 66 + colp) << 7) + ((((ich >> 3)) ^ (colp & 7)) << 4) + ((ich & 7) << 1);
        Xw[byte >> 2] = u;
      }
    }
  }

  f32x4 acc[4][2];
  #pragma unroll
  for (int m = 0; m < 4; ++m)
    #pragma unroll
    for (int n = 0; n < 2; ++n) acc[m][n] = (f32x4){0.f, 0.f, 0.f, 0.f};

  const int4* wmg = (const int4*)(WS + WMOD_OFF);
  const bf16x8* Xv = (const bf16x8*)Xl;
  const bf16x8* Wv = (const bf16x8*)Wl;
  int4* Wst = (int4*)Wl;

  for (int dy = 0; dy < 3; ++dy) {
    __syncthreads();
    for (int i = 0; i < 6; ++i) {
      const int idx = i * 256 + t;
      const int o = idx / 24;
      const int g = idx - o * 24;
      const int dx = g >> 3, gg = g & 7;
      const int4 v = wmg[((size_t)(b * 64 + o) * 9 + dy * 3 + dx) * 8 + gg];
      Wst[o * 24 + dx * 8 + (gg ^ (o & 7))] = v;
    }
    __syncthreads();

    #pragma unroll
    for (int dx = 0; dx < 3; ++dx) {
      #pragma unroll
      for (int kh = 0; kh < 2; ++kh) {
        const int kg = kh * 4 + l4;
        bf16x8 afr[4];
        #pragma unroll
        for (int m = 0; m < 4; ++m) {
          const int o = m * 16 + l15;
          afr[m] = Wv[o * 24 + dx * 8 + (kg ^ (o & 7))];
        }
        bf16x8 bfr[2];
        #pragma unroll
        for (int n = 0; n < 2; ++n) {
          const int pbase = w * 32 + n * 16;
          const int rip = pbase >> 6;
          const int col = (pbase & 63) + l15;
          const int row3 = rip + dy;
          const int colp = col + dx;
          bfr[n] = Xv[((row3 * 66 + colp) << 3) + (kg ^ (colp & 7))];
        }
        #pragma unroll
        for (int m = 0; m < 4; ++m)
          #pragma unroll
          for (int n = 0; n < 2; ++n)
            acc[m][n] = __builtin_amdgcn_mfma_f32_16x16x32_bf16(
                afr[m], bfr[n], acc[m][n], 0, 0, 0);
      }
    }
  }

  #pragma unroll
  for (int m = 0; m < 4; ++m) {
    #pragma unroll
    for (int n = 0; n < 2; ++n) {
      const int pbase = w * 32 + n * 16;
      const int rip = pbase >> 6;
      const int cb = (pbase & 63) + l15;
      #pragma unroll
      for (int j = 0; j < 4; ++j) {
        const int o = m * 16 + l4 * 4 + j;
        WS[Y_OFF + ((size_t)(b * 64 + o) << 12) + ((2 * rg + rip) << 6) + cb] =
            acc[m][n][j];
      }
    }
  }

  __syncthreads();
  float* sred = (float*)Wl;
  {
    #pragma unroll
    for (int m = 0; m < 4; ++m) {
      #pragma unroll
      for (int j = 0; j < 4; ++j) {
        float a0 = acc[m][0][j], a1 = acc[m][1][j];
        float s1 = a0 + a1;
        float s2 = a0 * a0 + a1 * a1;
        #pragma unroll
        for (int off = 1; off < 16; off <<= 1) {
          s1 += __shfl_xor(s1, off);
          s2 += __shfl_xor(s2, off);
        }
        if (l15 == 0) {
          const int o = m * 16 + l4 * 4 + j;
          sred[(w * 64 + o) * 2 + 0] = s1;
          sred[(w * 64 + o) * 2 + 1] = s2;
        }
      }
    }
  }
  __syncthreads();
  if (t < 128) {
    const int o = t >> 1, wh = t & 1;
    float s = sred[o * 2 + wh] + sred[(64 + o) * 2 + wh] +
              sred[(128 + o) * 2 + wh] + sred[(192 + o) * 2 + wh];
    WS[P_OFF + (((size_t)b * 32 + rg) * 64 + o) * 2 + wh] = s;
  }
}

// ---------------------------------------------------------------------------
// g2: fused stats + affine/leaky + G GEMM.
// grid 256 = (b, 64-px chunk), 512 threads (8 waves). Per block:
//  phase0: reduce conv partials -> per-channel A,B
//  phase1: stage y chunk -> LDS ft[c][px] with affine+leaky applied
//  phase2: wave w: px = chunk*64 + w*8 + k, lane = o;
//          acc[k] += ft[c][px] (LDS float4 broadcast) * wcreg[c]
// ---------------------------------------------------------------------------
__global__ __launch_bounds__(512) void g2_kernel(
    const float* __restrict__ scale2, const float* __restrict__ shiftp,
    const float* __restrict__ act_b) {
  const int b = blockIdx.x >> 6;
  const int chunk = blockIdx.x & 63;
  const int pxbase = chunk << 6;
  const int t = threadIdx.x;
  const int wave = t >> 6, lane = t & 63;

  __shared__ __align__(16) float ft[64][68];
  __shared__ float A_sh[64], B_sh[64];
  __shared__ float red[512];

  // Wc column preload (independent of LDS phases; hoisted by compiler)
  float wcreg[64];
  #pragma unroll
  for (int c = 0; c < 64; ++c) wcreg[c] = WS[WC_OFF + c * 64 + lane];
  const float bcv = WS[BC_OFF + lane];

  // ---- phase 0: stats -> A,B
  if (t < 256) {
    const int c = t & 63, qq = t >> 6;
    const float* p = WS + P_OFF + ((size_t)(b * 32 + qq * 8) * 64 + c) * 2;
    float S1 = 0.f, S2 = 0.f;
    #pragma unroll
    for (int r = 0; r < 8; ++r) { S1 += p[r * 128]; S2 += p[r * 128 + 1]; }
    red[t] = S1; red[256 + t] = S2;
  }
  __syncthreads();
  if (t < 64) {
    const float S1 = red[t] + red[64 + t] + red[128 + t] + red[192 + t];
    const float S2 = red[256 + t] + red[320 + t] + red[384 + t] + red[448 + t];
    const float mu = S1 * (1.f / 4096.f);
    const float var = S2 * (1.f / 4096.f) - mu * mu;
    const float dm = WS[DM_OFF + b * 64 + t];
    const float rstd = rsqrtf(dm * dm * var + 1e-5f);
    const float A = dm * rstd * scale2[b * 64 + t];
    A_sh[t] = A;
    B_sh[t] = -mu * A + shiftp[b * 64 + t] + act_b[t];
  }
  __syncthreads();

  // ---- phase 1: stage y chunk with affine + leaky -> ft[c][px]
  {
    const int c = t >> 3, slot = t & 7;
    const float A = A_sh[c], B = B_sh[c];
    const float* yrow = WS + Y_OFF + ((size_t)(b * 64 + c) << 12) + pxbase;
    #pragma unroll
    for (int it = 0; it < 2; ++it) {
      const int px4 = (it * 8 + slot) * 4;
      const float4 y4 = *(const float4*)(yrow + px4);
      float4 f;
      float u;
      u = y4.x * A + B; f.x = (u > 0.f ? u : 0.2f * u) * SQRT2F;
      u = y4.y * A + B; f.y = (u > 0.f ? u : 0.2f * u) * SQRT2F;
      u = y4.z * A + B; f.z = (u > 0.f ? u : 0.2f * u) * SQRT2F;
      u = y4.w * A + B; f.w = (u > 0.f ? u : 0.2f * u) * SQRT2F;
      *(float4*)&ft[c][px4] = f;
    }
  }
  __syncthreads();

  // ---- phase 2: G[b][px][o] = bc[o] + sum_c ft[c][px] * Wc[c][o]
  float acc[8];
  #pragma unroll
  for (int k = 0; k < 8; ++k) acc[k] = bcv;
  const int p0 = wave * 8;
  #pragma unroll
  for (int c = 0; c < 64; ++c) {
    const float4 fa = *(const float4*)&ft[c][p0];
    const float4 fb = *(const float4*)&ft[c][p0 + 4];
    const float wv = wcreg[c];
    acc[0] = fmaf(fa.x, wv, acc[0]);
    acc[1] = fmaf(fa.y, wv, acc[1]);
    acc[2] = fmaf(fa.z, wv, acc[2]);
    acc[3] = fmaf(fa.w, wv, acc[3]);
    acc[4] = fmaf(fb.x, wv, acc[4]);
    acc[5] = fmaf(fb.y, wv, acc[5]);
    acc[6] = fmaf(fb.z, wv, acc[6]);
    acc[7] = fmaf(fb.w, wv, acc[7]);
  }
  float* g = WS + G_OFF + (((size_t)b * 4096 + pxbase + p0) << 6) + lane;
  #pragma unroll
  for (int k = 0; k < 8; ++k) g[k << 6] = acc[k];
}

// ---------------------------------------------------------------------------
// Output: local-ensemble gather + affine. 4 threads per query.
// ---------------------------------------------------------------------------
__global__ __launch_bounds__(256) void out_kernel(float* __restrict__ out) {
  const int t = threadIdx.x;
  const int pl = t >> 2, sub = t & 3;
  const int gq = blockIdx.x * 64 + pl;
  const int b = gq >> 16;
  const int q = gq & 65535;
  const int oy = q >> 8, ox = q & 255;

  const float cy0 = -1.f + (2.f * oy + 1.f) * (1.f / 256.f);
  const float cx0 = -1.f + (2.f * ox + 1.f) * (1.f / 256.f);
  const float lo = -1.f + 1e-6f, hi = 1.f - 1e-6f;

  int cell[4];
  float area[4], rely[4], relx[4];
  int j = 0;
  #pragma unroll
  for (int vx = -1; vx <= 1; vx += 2) {
    #pragma unroll
    for (int vy = -1; vy <= 1; vy += 2) {
      float cy = cy0 + (float)vx * (1.f / 64.f) + 1e-6f;
      cy = fminf(fmaxf(cy, lo), hi);
      float cx = cx0 + (float)vy * (1.f / 64.f) + 1e-6f;
      cx = fminf(fmaxf(cx, lo), hi);
      const float fy = floorf((cy + 1.f) * 0.5f * 64.f);
      const float fx = floorf((cx + 1.f) * 0.5f * 64.f);
      const int iy = (int)fminf(fmaxf(fy, 0.f), 63.f);
      const int ix = (int)fminf(fmaxf(fx, 0.f), 63.f);
      const float qy = -1.f + (2.f * iy + 1.f) * (1.f / 64.f);
      const float qx = -1.f + (2.f * ix + 1.f) * (1.f / 64.f);
      const float ry_ = (cy0 - qy) * 64.f;
      const float rx_ = (cx0 - qx) * 64.f;
      cell[j] = iy * 64 + ix;
      rely[j] = ry_; relx[j] = rx_;
      area[j] = fabsf(ry_ * rx_) + 1e-9f;
      ++j;
    }
  }
  const float tot = area[0] + area[1] + area[2] + area[3];
  float wgt[4];
  #pragma unroll
  for (int k = 0; k < 4; ++k) wgt[k] = area[3 - k] / tot;
  const float swy = wgt[0] * rely[0] + wgt[1] * rely[1] + wgt[2] * rely[2] + wgt[3] * rely[3];
  const float swx = wgt[0] * relx[0] + wgt[1] * relx[1] + wgt[2] * relx[2] + wgt[3] * relx[3];

  const int chb = sub * 16;
  const float4* W64 = (const float4*)(WS + WC_OFF + 64 * 64 + chb);
  const float4* W65 = (const float4*)(WS + WC_OFF + 65 * 64 + chb);
  float4 r[4];
  #pragma unroll
  for (int k = 0; k < 4; ++k) {
    const float4 a = W64[k], bv = W65[k];
    r[k].x = swy * a.x + swx * bv.x;
    r[k].y = swy * a.y + swx * bv.y;
    r[k].z = swy * a.z + swx * bv.z;
    r[k].w = swy * a.w + swx * bv.w;
  }
  #pragma unroll
  for (int jj = 0; jj < 4; ++jj) {
    const float4* gp = (const float4*)(WS + G_OFF + (((size_t)b * 4096 + cell[jj]) << 6) + chb);
    const float wv = wgt[jj];
    #pragma unroll
    for (int k = 0; k < 4; ++k) {
      const float4 gv = gp[k];
      r[k].x += wv * gv.x; r[k].y += wv * gv.y;
      r[k].z += wv * gv.z; r[k].w += wv * gv.w;
    }
  }
  float4* op = (float4*)(out + ((size_t)gq << 6) + chb);
  #pragma unroll
  for (int k = 0; k < 4; ++k) op[k] = r[k];
}

// ---------------------------------------------------------------------------
extern "C" void kernel_launch(void* const* d_in, const int* in_sizes, int n_in,
                              void* d_out, int out_size, void* d_ws, size_t ws_size,
                              hipStream_t stream) {
  (void)in_sizes; (void)n_in; (void)out_size; (void)d_ws; (void)ws_size;
  const float* x      = (const float*)d_in[0];
  const float* scale1 = (const float*)d_in[1];
  const float* scale2 = (const float*)d_in[2];
  const float* shiftp = (const float*)d_in[3];
  const float* mod_w  = (const float*)d_in[4];
  const float* mod_b  = (const float*)d_in[5];
  const float* conv_w = (const float*)d_in[6];
  const float* act_b  = (const float*)d_in[7];
  const float* w1     = (const float*)d_in[8];
  const float* b1     = (const float*)d_in[9];
  const float* w2     = (const float*)d_in[10];
  const float* b2     = (const float*)d_in[11];
  float* out = (float*)d_out;

  hipLaunchKernelGGL(prepwc_kernel, dim3(21), dim3(256), 0, stream,
                     scale1, mod_w, mod_b, conv_w, b1, w2, b2, w1);
  hipLaunchKernelGGL(conv_kernel, dim3(128), dim3(256), 0, stream, x);
  hipLaunchKernelGGL(g2_kernel, dim3(256), dim3(512), 0, stream,
                     scale2, shiftp, act_b);
  hipLaunchKernelGGL(out_kernel, dim3(4096), dim3(256), 0, stream, out);
}

// Round 5
// 91.949 us; speedup vs baseline: 1.9957x; 1.0881x over previous
//
#include <hip/hip_runtime.h>

#define SQRT2F 1.41421356237309515f

typedef __attribute__((ext_vector_type(8))) short bf16x8;
typedef __attribute__((ext_vector_type(4))) float f32x4;

enum : int {
  S_OFF    = 0,          // s[b][i]                 : 256
  DM_OFF   = 256,        // demod[b][o]             : 256
  BC_OFF   = 512,        // bc[o]                   : 64
  WC_OFF   = 1024,       // Wc[66][64]              : 4224 (ends 5248)
  P_OFF    = 8192,       // partials[b][64][64][2]  : 32768 (ends 40960)
  WMOD_OFF = 40960,      // bf16 Wmod[b][o][9][64]  : 147456 ushort = 73728 fl
  Y_OFF    = 131072,     // y[b][c][4096] raw conv  : 1048576
  WS_FLOATS = Y_OFF + 1048576
};

__device__ __align__(16) float WS[WS_FLOATS];

__device__ __forceinline__ unsigned short f2bf(float v) {
  unsigned int u = __float_as_uint(v);
  u += 0x7fffu + ((u >> 16) & 1u);
  return (unsigned short)(u >> 16);
}

// ---------------------------------------------------------------------------
// prepwc: blocks 0-3 = per-b modulation s, demod, bc, bf16 Wmod.
//         blocks 4-20 = Wc = w1 @ w2.
// ---------------------------------------------------------------------------
__global__ __launch_bounds__(256) void prepwc_kernel(
    const float* __restrict__ scale1, const float* __restrict__ mod_w,
    const float* __restrict__ mod_b,  const float* __restrict__ conv_w,
    const float* __restrict__ b1,     const float* __restrict__ w2,
    const float* __restrict__ b2,     const float* __restrict__ w1) {
  const int t = threadIdx.x;

  if (blockIdx.x >= 4) {
    const int idx = (blockIdx.x - 4) * 256 + t;
    if (idx < 66 * 64) {
      const int c = idx >> 6, o = idx & 63;
      const float* r1 = w1 + c * 256;
      float acc = 0.f;
      for (int k = 0; k < 256; ++k) acc += r1[k] * w2[k * 64 + o];
      WS[WC_OFF + idx] = acc;
    }
    return;
  }

  const int b = blockIdx.x;
  const int i = t >> 2, qq = t & 3;
  __shared__ float part[256];
  __shared__ float s_sh[64];

  // ---- s[b][i] = scale1[b] . mod_w[i] + mod_b[i]
  {
    const float* sv = scale1 + b * 512 + qq * 128;
    const float* mw = mod_w + i * 512 + qq * 128;
    float p = 0.f;
    for (int k = 0; k < 128; ++k) p += sv[k] * mw[k];
    part[t] = p;
  }
  __syncthreads();
  if (qq == 0) {
    float sval = part[t] + part[t + 1] + part[t + 2] + part[t + 3] + mod_b[i];
    s_sh[i] = sval;
    WS[S_OFF + b * 64 + i] = sval;
  }
  __syncthreads();

  // ---- demod[b][o] (f32, identical to reference)
  {
    const int o = i;
    const float* cw = conv_w + o * 576 + qq * 144;
    float d = 0.f;
    for (int ii = 0; ii < 16; ++ii) {
      float ss = s_sh[qq * 16 + ii];
      float wsq = 0.f;
      #pragma unroll
      for (int k = 0; k < 9; ++k) { float w = cw[ii * 9 + k]; wsq += w * w; }
      d += ss * ss * wsq;
    }
    part[t] = d;
  }
  __syncthreads();
  if (qq == 0)
    WS[DM_OFF + b * 64 + i] =
        rsqrtf(part[t] + part[t + 1] + part[t + 2] + part[t + 3] + 1e-8f);
  __syncthreads();

  // ---- bc[o] = b1 . w2[:,o] + b2[o]
  {
    const int o = i;
    const int kb = qq * 64;
    float a = 0.f;
    for (int k = 0; k < 64; ++k) a += b1[kb + k] * w2[(kb + k) * 64 + o];
    part[t] = a;
  }
  __syncthreads();
  if (qq == 0)
    WS[BC_OFF + i] = part[t] + part[t + 1] + part[t + 2] + part[t + 3] + b2[i];

  // ---- Wmod bf16 [(b*64+o)*9 + tap]*64 + ich, coalesced READS of conv_w
  unsigned short* wm = (unsigned short*)(WS + WMOD_OFF);
  for (int it = 0; it < 144; ++it) {
    const int ridx = it * 256 + t;            // = o*576 + ich*9 + tap
    const int o = ridx / 576;
    const int rem = ridx - o * 576;
    const int ich = rem / 9;
    const int tap = rem - ich * 9;
    wm[(size_t)b * 36864 + o * 576 + tap * 64 + ich] =
        f2bf(conv_w[ridx] * s_sh[ich]);
  }
}

// ---------------------------------------------------------------------------
// MFMA conv: block = (b, row r). 256 blocks -> every CU busy.
// LDS: Xl = bf16 x-halo [3 rows][66 cols][64 ich], XOR-swizzled 16B groups.
//      Wl = bf16 weight slice [64 o][3 taps][64 ich], XOR-swizzled.
// Wave w: 64o x 16px (4m x 1n register tile), 72 MFMAs.
// ---------------------------------------------------------------------------
__global__ __launch_bounds__(256) void conv_kernel(const float* __restrict__ x) {
  const int b = blockIdx.x >> 6;
  const int r = blockIdx.x & 63;
  const int t = threadIdx.x;
  const int w = t >> 6, lane = t & 63;
  const int l15 = lane & 15, l4 = lane >> 4;

  __shared__ __align__(16) unsigned short Xl[3 * 66 * 64];   // 25344 B
  __shared__ __align__(16) unsigned short Wl[64 * 24 * 8];   // 24576 B

  {
    int4* Xz = (int4*)Xl;
    int4 z; z.x = z.y = z.z = z.w = 0;
    for (int idx = t; idx < 1584; idx += 256) Xz[idx] = z;
  }
  __syncthreads();

  {
    const int col = t & 63;
    const int tq = t >> 6;
    unsigned int* Xw = (unsigned int*)Xl;
    for (int it = 0; it < 24; ++it) {
      const int task = it * 4 + tq;          // 0..95 = row3*32 + ichpair
      const int row3 = task >> 5;
      const int ich = (task & 31) * 2;
      const int rr = r - 1 + row3;
      if (rr >= 0 && rr < 64) {
        const float* xb = x + ((size_t)(b * 64 + ich) << 12) + (rr << 6) + col;
        const float v0 = xb[0];
        const float v1 = xb[4096];
        const unsigned int u = (unsigned int)f2bf(v0) | ((unsigned int)f2bf(v1) << 16);
        const int colp = col + 1;
        const int byte = ((row3 * 66 + colp) << 7) + ((((ich >> 3)) ^ (colp & 7)) << 4) + ((ich & 7) << 1);
        Xw[byte >> 2] = u;
      }
    }
  }

  f32x4 acc[4];
  #pragma unroll
  for (int m = 0; m < 4; ++m) acc[m] = (f32x4){0.f, 0.f, 0.f, 0.f};

  const int4* wmg = (const int4*)(WS + WMOD_OFF);
  const bf16x8* Xv = (const bf16x8*)Xl;
  const bf16x8* Wv = (const bf16x8*)Wl;
  int4* Wst = (int4*)Wl;

  for (int dy = 0; dy < 3; ++dy) {
    __syncthreads();
    for (int i = 0; i < 6; ++i) {
      const int idx = i * 256 + t;
      const int o = idx / 24;
      const int g = idx - o * 24;
      const int dx = g >> 3, gg = g & 7;
      const int4 v = wmg[((size_t)(b * 64 + o) * 9 + dy * 3 + dx) * 8 + gg];
      Wst[o * 24 + dx * 8 + (gg ^ (o & 7))] = v;
    }
    __syncthreads();

    #pragma unroll
    for (int dx = 0; dx < 3; ++dx) {
      #pragma unroll
      for (int kh = 0; kh < 2; ++kh) {
        const int kg = kh * 4 + l4;
        bf16x8 afr[4];
        #pragma unroll
        for (int m = 0; m < 4; ++m) {
          const int o = m * 16 + l15;
          afr[m] = Wv[o * 24 + dx * 8 + (kg ^ (o & 7))];
        }
        const int colp = w * 16 + l15 + dx;
        const bf16x8 bfr = Xv[((dy * 66 + colp) << 3) + (kg ^ (colp & 7))];
        #pragma unroll
        for (int m = 0; m < 4; ++m)
          acc[m] = __builtin_amdgcn_mfma_f32_16x16x32_bf16(
              afr[m], bfr, acc[m], 0, 0, 0);
      }
    }
  }

  // store raw y. D layout: col(px) = lane&15, row(o) = (lane>>4)*4 + j
  const int cb = w * 16 + l15;
  #pragma unroll
  for (int m = 0; m < 4; ++m) {
    #pragma unroll
    for (int j = 0; j < 4; ++j) {
      const int o = m * 16 + l4 * 4 + j;
      WS[Y_OFF + ((size_t)(b * 64 + o) << 12) + (r << 6) + cb] = acc[m][j];
    }
  }

  // per-block partial sums over this row's 64 px
  __syncthreads();
  float* sred = (float*)Wl;                 // [4 waves][64 o][2]
  {
    #pragma unroll
    for (int m = 0; m < 4; ++m) {
      #pragma unroll
      for (int j = 0; j < 4; ++j) {
        float s1 = acc[m][j];
        float s2 = acc[m][j] * acc[m][j];
        #pragma unroll
        for (int off = 1; off < 16; off <<= 1) {
          s1 += __shfl_xor(s1, off);
          s2 += __shfl_xor(s2, off);
        }
        if (l15 == 0) {
          const int o = m * 16 + l4 * 4 + j;
          sred[(w * 64 + o) * 2 + 0] = s1;
          sred[(w * 64 + o) * 2 + 1] = s2;
        }
      }
    }
  }
  __syncthreads();
  if (t < 128) {
    const int o = t >> 1, wh = t & 1;
    float s = sred[o * 2 + wh] + sred[(64 + o) * 2 + wh] +
              sred[(128 + o) * 2 + wh] + sred[(192 + o) * 2 + wh];
    WS[P_OFF + (((size_t)b * 64 + r) * 64 + o) * 2 + wh] = s;
  }
}

// ---------------------------------------------------------------------------
// gout: fused stats + affine/leaky + G-on-LDS + local-ensemble output.
// grid 256 = (b, ty, tx): 32x32 query tile needs a 10x10 cell patch.
// 512 threads (8 waves).
// ---------------------------------------------------------------------------
__global__ __launch_bounds__(512) void gout_kernel(
    const float* __restrict__ scale2, const float* __restrict__ shiftp,
    const float* __restrict__ act_b,  float* __restrict__ out) {
  const int bid = blockIdx.x;
  const int b = bid >> 6;
  const int ty = (bid >> 3) & 7;
  const int tx = bid & 7;
  const int t = threadIdx.x;
  const int lane = t & 63;

  __shared__ float A_sh[64], B_sh[64];
  __shared__ float red[1024];
  __shared__ __align__(16) float ft_l[64][100];   // 25.6 KB
  __shared__ __align__(16) float G_l[100][68];    // 27.2 KB (pad 68 vs bank conflicts)

  // Wc column + bc preload (lane = o)
  float wcreg[64];
  #pragma unroll
  for (int c = 0; c < 64; ++c) wcreg[c] = WS[WC_OFF + c * 64 + lane];
  const float bcv = WS[BC_OFF + lane];

  // ---- phase 0: stats -> A,B
  {
    const int c = t & 63, qq = t >> 6;       // qq = 0..7, 8 row-groups each
    const float* p = WS + P_OFF + (((size_t)b * 64 + qq * 8) * 64 + c) * 2;
    float S1 = 0.f, S2 = 0.f;
    #pragma unroll
    for (int rr = 0; rr < 8; ++rr) { S1 += p[rr * 128]; S2 += p[rr * 128 + 1]; }
    red[t] = S1; red[512 + t] = S2;
  }
  __syncthreads();
  if (t < 64) {
    float S1 = 0.f, S2 = 0.f;
    #pragma unroll
    for (int qq = 0; qq < 8; ++qq) { S1 += red[qq * 64 + t]; S2 += red[512 + qq * 64 + t]; }
    const float mu = S1 * (1.f / 4096.f);
    const float var = S2 * (1.f / 4096.f) - mu * mu;
    const float dm = WS[DM_OFF + b * 64 + t];
    const float rstd = rsqrtf(dm * dm * var + 1e-5f);
    const float A = dm * rstd * scale2[b * 64 + t];
    A_sh[t] = A;
    B_sh[t] = -mu * A + shiftp[b * 64 + t] + act_b[t];
  }
  __syncthreads();

  // ---- phase 1: stage 10x10 cell patch with affine + leaky -> ft_l[c][cell]
  const int cy_base = ty * 8 - 1, cx_base = tx * 8 - 1;
  {
    const int c = t >> 3, slot = t & 7;
    const float A = A_sh[c], B = B_sh[c];
    const float* yrow = WS + Y_OFF + ((size_t)(b * 64 + c) << 12);
    for (int cell = slot; cell < 100; cell += 8) {
      const int li = cell / 10, lj = cell - li * 10;
      const int ciy = cy_base + li, cix = cx_base + lj;
      if (ciy >= 0 && ciy < 64 && cix >= 0 && cix < 64) {
        const float u = yrow[(ciy << 6) + cix] * A + B;
        ft_l[c][cell] = (u > 0.f ? u : 0.2f * u) * SQRT2F;
      }
    }
  }
  __syncthreads();

  // ---- phase 2: G_l[cell][o] = bc[o] + sum_c ft_l[c][cell] * Wc[c][o]
  {
    const int w = t >> 6;
    #pragma unroll
    for (int p = 0; p < 4; ++p) {
      const int cb = p * 32 + w * 4;
      if (cb < 100) {
        float a0 = bcv, a1 = bcv, a2 = bcv, a3 = bcv;
        #pragma unroll
        for (int c = 0; c < 64; ++c) {
          const float4 fv = *(const float4*)&ft_l[c][cb];
          const float wv = wcreg[c];
          a0 = fmaf(fv.x, wv, a0); a1 = fmaf(fv.y, wv, a1);
          a2 = fmaf(fv.z, wv, a2); a3 = fmaf(fv.w, wv, a3);
        }
        G_l[cb + 0][lane] = a0; G_l[cb + 1][lane] = a1;
        G_l[cb + 2][lane] = a2; G_l[cb + 3][lane] = a3;
      }
    }
  }

  // rel-term Wc rows 64,65 (per quad-sub channel range)
  const int sub = t & 3, chb = sub * 16;
  float4 wa[4], wb[4];
  #pragma unroll
  for (int k = 0; k < 4; ++k) {
    wa[k] = *(const float4*)(WS + WC_OFF + 64 * 64 + chb + k * 4);
    wb[k] = *(const float4*)(WS + WC_OFF + 65 * 64 + chb + k * 4);
  }
  __syncthreads();

  // ---- phase 3: 1024 queries, 4 threads/query, 8 passes
  const float lo = -1.f + 1e-6f, hi = 1.f - 1e-6f;
  #pragma unroll 1
  for (int pass = 0; pass < 8; ++pass) {
    const int qi = pass * 128 + (t >> 2);
    const int oy = (ty << 5) + (qi >> 5), ox = (tx << 5) + (qi & 31);

    const float cy0 = -1.f + (2.f * oy + 1.f) * (1.f / 256.f);
    const float cx0 = -1.f + (2.f * ox + 1.f) * (1.f / 256.f);

    int lcell[4];
    float area[4], rely[4], relx[4];
    int j = 0;
    #pragma unroll
    for (int vx = -1; vx <= 1; vx += 2) {
      #pragma unroll
      for (int vy = -1; vy <= 1; vy += 2) {
        float cy = cy0 + (float)vx * (1.f / 64.f) + 1e-6f;
        cy = fminf(fmaxf(cy, lo), hi);
        float cx = cx0 + (float)vy * (1.f / 64.f) + 1e-6f;
        cx = fminf(fmaxf(cx, lo), hi);
        const float fy = floorf((cy + 1.f) * 32.f);
        const float fx = floorf((cx + 1.f) * 32.f);
        const int iy = (int)fminf(fmaxf(fy, 0.f), 63.f);
        const int ix = (int)fminf(fmaxf(fx, 0.f), 63.f);
        const float qy = -1.f + (2.f * iy + 1.f) * (1.f / 64.f);
        const float qx = -1.f + (2.f * ix + 1.f) * (1.f / 64.f);
        const float ry_ = (cy0 - qy) * 64.f;
        const float rx_ = (cx0 - qx) * 64.f;
        lcell[j] = (iy - cy_base) * 10 + (ix - cx_base);
        rely[j] = ry_; relx[j] = rx_;
        area[j] = fabsf(ry_ * rx_) + 1e-9f;
        ++j;
      }
    }
    const float tot = area[0] + area[1] + area[2] + area[3];
    float wgt[4];
    #pragma unroll
    for (int k = 0; k < 4; ++k) wgt[k] = area[3 - k] / tot;   // diagonal swap
    const float swy = wgt[0] * rely[0] + wgt[1] * rely[1] + wgt[2] * rely[2] + wgt[3] * rely[3];
    const float swx = wgt[0] * relx[0] + wgt[1] * relx[1] + wgt[2] * relx[2] + wgt[3] * relx[3];

    float4 r[4];
    #pragma unroll
    for (int k = 0; k < 4; ++k) {
      r[k].x = swy * wa[k].x + swx * wb[k].x;
      r[k].y = swy * wa[k].y + swx * wb[k].y;
      r[k].z = swy * wa[k].z + swx * wb[k].z;
      r[k].w = swy * wa[k].w + swx * wb[k].w;
    }
    #pragma unroll
    for (int jj = 0; jj < 4; ++jj) {
      const float4* gp = (const float4*)&G_l[lcell[jj]][chb];
      const float wv = wgt[jj];
      #pragma unroll
      for (int k = 0; k < 4; ++k) {
        const float4 gv = gp[k];
        r[k].x += wv * gv.x; r[k].y += wv * gv.y;
        r[k].z += wv * gv.z; r[k].w += wv * gv.w;
      }
    }
    const size_t gq = ((size_t)b << 16) + (oy << 8) + ox;
    float4* op = (float4*)(out + (gq << 6) + chb);
    #pragma unroll
    for (int k = 0; k < 4; ++k) op[k] = r[k];
  }
}

// ---------------------------------------------------------------------------
extern "C" void kernel_launch(void* const* d_in, const int* in_sizes, int n_in,
                              void* d_out, int out_size, void* d_ws, size_t ws_size,
                              hipStream_t stream) {
  (void)in_sizes; (void)n_in; (void)out_size; (void)d_ws; (void)ws_size;
  const float* x      = (const float*)d_in[0];
  const float* scale1 = (const float*)d_in[1];
  const float* scale2 = (const float*)d_in[2];
  const float* shiftp = (const float*)d_in[3];
  const float* mod_w  = (const float*)d_in[4];
  const float* mod_b  = (const float*)d_in[5];
  const float* conv_w = (const float*)d_in[6];
  const float* act_b  = (const float*)d_in[7];
  const float* w1     = (const float*)d_in[8];
  const float* b1     = (const float*)d_in[9];
  const float* w2     = (const float*)d_in[10];
  const float* b2     = (const float*)d_in[11];
  float* out = (float*)d_out;

  hipLaunchKernelGGL(prepwc_kernel, dim3(21), dim3(256), 0, stream,
                     scale1, mod_w, mod_b, conv_w, b1, w2, b2, w1);
  hipLaunchKernelGGL(conv_kernel, dim3(256), dim3(256), 0, stream, x);
  hipLaunchKernelGGL(gout_kernel, dim3(256), dim3(512), 0, stream,
                     scale2, shiftp, act_b, out);
}

// Round 6
// 70.159 us; speedup vs baseline: 2.6155x; 1.3106x over previous
//
#include <hip/hip_runtime.h>

#define SQRT2F 1.41421356237309515f

typedef __attribute__((ext_vector_type(8))) short bf16x8;
typedef __attribute__((ext_vector_type(4))) float f32x4;

enum : int {
  DM_OFF   = 0,          // demod[b][o]             : 256
  BC_OFF   = 256,        // bc[o]                   : 64
  WC_OFF   = 1024,       // Wc[66][64]              : 4224 (ends 5248)
  P_OFF    = 8192,       // partials[b][64][64][2]  : 32768 (ends 40960)
  Y_OFF    = 65536,      // y[b][px][c] raw conv    : 1048576
  WS_FLOATS = Y_OFF + 1048576
};

__device__ __align__(16) float WS[WS_FLOATS];

__device__ __forceinline__ unsigned short f2bf(float v) {
  unsigned int u = __float_as_uint(v);
  u += 0x7fffu + ((u >> 16) & 1u);
  return (unsigned short)(u >> 16);
}

// ---------------------------------------------------------------------------
// fused1: blocks 0-255   = MFMA conv (b = bid>>6, row r = bid&63), inline s,
//                          input-modulated staging (x*s), raw conv_w gather.
//         blocks 256-259 = s + demod for b = bid-256.
//         blocks 260-276 = Wc = w1@w2 (+ bc in spare threads of last block).
// ---------------------------------------------------------------------------
__global__ __launch_bounds__(256) void fused1_kernel(
    const float* __restrict__ x,      const float* __restrict__ scale1,
    const float* __restrict__ mod_w,  const float* __restrict__ mod_b,
    const float* __restrict__ conv_w, const float* __restrict__ b1,
    const float* __restrict__ w2,     const float* __restrict__ b2,
    const float* __restrict__ w1) {
  const int bid = blockIdx.x;
  const int t = threadIdx.x;

  __shared__ __align__(16) unsigned short Xl[3 * 66 * 64];   // 25344 B
  __shared__ __align__(16) unsigned short Wl[64 * 24 * 8];   // 24576 B
  __shared__ float part[256];
  __shared__ float s_sh[64];

  if (bid >= 256) {
    if (bid < 260) {
      // ---- s + demod for b
      const int b = bid - 256;
      const int i = t >> 2, qq = t & 3;
      {
        const float* sv = scale1 + b * 512 + qq * 128;
        const float* mw = mod_w + i * 512 + qq * 128;
        float p = 0.f;
        for (int k = 0; k < 128; ++k) p += sv[k] * mw[k];
        part[t] = p;
      }
      __syncthreads();
      if (qq == 0)
        s_sh[i] = part[t] + part[t + 1] + part[t + 2] + part[t + 3] + mod_b[i];
      __syncthreads();
      {
        const int o = i;
        const float* cw = conv_w + o * 576 + qq * 144;
        float d = 0.f;
        for (int ii = 0; ii < 16; ++ii) {
          float ss = s_sh[qq * 16 + ii];
          float wsq = 0.f;
          #pragma unroll
          for (int k = 0; k < 9; ++k) { float w = cw[ii * 9 + k]; wsq += w * w; }
          d += ss * ss * wsq;
        }
        part[t] = d;
      }
      __syncthreads();
      if (qq == 0)
        WS[DM_OFF + b * 64 + i] =
            rsqrtf(part[t] + part[t + 1] + part[t + 2] + part[t + 3] + 1e-8f);
    } else {
      // ---- Wc = w1 @ w2 ([66,256]@[256,64]); bc in spare threads
      const int idx = (bid - 260) * 256 + t;
      if (idx < 4224) {
        const int c = idx >> 6, o = idx & 63;
        const float* r1 = w1 + c * 256;
        float acc = 0.f;
        for (int k = 0; k < 256; ++k) acc += r1[k] * w2[k * 64 + o];
        WS[WC_OFF + idx] = acc;
      } else if (idx < 4288) {
        const int o = idx - 4224;
        float a = 0.f;
        for (int k = 0; k < 256; ++k) a += b1[k] * w2[k * 64 + o];
        WS[BC_OFF + o] = a + b2[o];
      }
    }
    return;
  }

  // ======================= conv role =======================
  const int b = bid >> 6;
  const int r = bid & 63;
  const int w = t >> 6, lane = t & 63;
  const int l15 = lane & 15, l4 = lane >> 4;

  // ---- inline s[b][*]
  {
    const int i = t >> 2, qq = t & 3;
    const float* sv = scale1 + b * 512 + qq * 128;
    const float* mw = mod_w + i * 512 + qq * 128;
    float p = 0.f;
    for (int k = 0; k < 128; ++k) p += sv[k] * mw[k];
    part[t] = p;
  }
  __syncthreads();
  if ((t & 3) == 0) {
    const int i = t >> 2;
    s_sh[i] = part[t] + part[t + 1] + part[t + 2] + part[t + 3] + mod_b[i];
  }
  // zero-init X (SAME-padding cols/rows) in the same phase
  {
    int4* Xz = (int4*)Xl;
    int4 z; z.x = z.y = z.z = z.w = 0;
    for (int idx = t; idx < 1584; idx += 256) Xz[idx] = z;
  }
  __syncthreads();

  // ---- stage x rows r-1..r+1 as bf16(x*s), XOR-swizzled
  {
    const int col = t & 63;
    const int tq = t >> 6;
    unsigned int* Xw = (unsigned int*)Xl;
    for (int it = 0; it < 24; ++it) {
      const int task = it * 4 + tq;          // 0..95 = row3*32 + ichpair
      const int row3 = task >> 5;
      const int ich = (task & 31) * 2;
      const int rr = r - 1 + row3;
      if (rr >= 0 && rr < 64) {
        const float* xb = x + ((size_t)(b * 64 + ich) << 12) + (rr << 6) + col;
        const float v0 = xb[0] * s_sh[ich];
        const float v1 = xb[4096] * s_sh[ich + 1];
        const unsigned int u = (unsigned int)f2bf(v0) | ((unsigned int)f2bf(v1) << 16);
        const int colp = col + 1;
        const int byte = ((row3 * 66 + colp) << 7) + ((((ich >> 3)) ^ (colp & 7)) << 4) + ((ich & 7) << 1);
        Xw[byte >> 2] = u;
      }
    }
  }

  f32x4 acc[4];
  #pragma unroll
  for (int m = 0; m < 4; ++m) acc[m] = (f32x4){0.f, 0.f, 0.f, 0.f};

  const bf16x8* Xv = (const bf16x8*)Xl;
  const bf16x8* Wv = (const bf16x8*)Wl;
  int4* Wst = (int4*)Wl;

  for (int dy = 0; dy < 3; ++dy) {
    __syncthreads();
    // gather raw conv_w[o][ich][dy*3+dx] -> bf16, swizzled
    for (int i = 0; i < 6; ++i) {
      const int idx = i * 256 + t;           // 0..1535 = o*24 + dx*8 + gg
      const int o = idx / 24;
      const int g = idx - o * 24;
      const int dx = g >> 3, gg = g & 7;
      const float* cw = conv_w + o * 576 + (gg * 8) * 9 + dy * 3 + dx;
      int4 v;
      v.x = (int)((unsigned int)f2bf(cw[0])  | ((unsigned int)f2bf(cw[9])  << 16));
      v.y = (int)((unsigned int)f2bf(cw[18]) | ((unsigned int)f2bf(cw[27]) << 16));
      v.z = (int)((unsigned int)f2bf(cw[36]) | ((unsigned int)f2bf(cw[45]) << 16));
      v.w = (int)((unsigned int)f2bf(cw[54]) | ((unsigned int)f2bf(cw[63]) << 16));
      Wst[o * 24 + dx * 8 + (gg ^ (o & 7))] = v;
    }
    __syncthreads();

    #pragma unroll
    for (int dx = 0; dx < 3; ++dx) {
      #pragma unroll
      for (int kh = 0; kh < 2; ++kh) {
        const int kg = kh * 4 + l4;
        bf16x8 afr[4];
        #pragma unroll
        for (int m = 0; m < 4; ++m) {
          const int o = m * 16 + l15;
          afr[m] = Wv[o * 24 + dx * 8 + (kg ^ (o & 7))];
        }
        const int colp = w * 16 + l15 + dx;
        const bf16x8 bfr = Xv[((dy * 66 + colp) << 3) + (kg ^ (colp & 7))];
        #pragma unroll
        for (int m = 0; m < 4; ++m)
          acc[m] = __builtin_amdgcn_mfma_f32_16x16x32_bf16(
              afr[m], bfr, acc[m], 0, 0, 0);
      }
    }
  }

  // ---- store raw y in [b][px][c] layout (float4 per m-group).
  // D layout: col(px) = lane&15, row(o) = (lane>>4)*4 + j
  {
    const int px = w * 16 + l15;
    float* yq = WS + Y_OFF + (((size_t)b * 4096 + r * 64 + px) << 6);
    #pragma unroll
    for (int m = 0; m < 4; ++m)
      *(f32x4*)(yq + m * 16 + l4 * 4) = acc[m];
  }

  // ---- per-block (row) partial sums
  __syncthreads();
  float* sred = (float*)Wl;                 // [4 waves][64 o][2]
  {
    #pragma unroll
    for (int m = 0; m < 4; ++m) {
      #pragma unroll
      for (int j = 0; j < 4; ++j) {
        float s1 = acc[m][j];
        float s2 = acc[m][j] * acc[m][j];
        #pragma unroll
        for (int off = 1; off < 16; off <<= 1) {
          s1 += __shfl_xor(s1, off);
          s2 += __shfl_xor(s2, off);
        }
        if (l15 == 0) {
          const int o = m * 16 + l4 * 4 + j;
          sred[(w * 64 + o) * 2 + 0] = s1;
          sred[(w * 64 + o) * 2 + 1] = s2;
        }
      }
    }
  }
  __syncthreads();
  if (t < 128) {
    const int o = t >> 1, wh = t & 1;
    float s = sred[o * 2 + wh] + sred[(64 + o) * 2 + wh] +
              sred[(128 + o) * 2 + wh] + sred[(192 + o) * 2 + wh];
    WS[P_OFF + (((size_t)b * 64 + r) * 64 + o) * 2 + wh] = s;
  }
}

// ---------------------------------------------------------------------------
// gout: fused stats + affine/leaky + G-on-LDS + local-ensemble output.
// grid 256 = (b, ty, tx): 32x32 query tile -> 10x10 cell patch. 512 threads.
// ---------------------------------------------------------------------------
__global__ __launch_bounds__(512) void gout_kernel(
    const float* __restrict__ scale2, const float* __restrict__ shiftp,
    const float* __restrict__ act_b,  float* __restrict__ out) {
  const int bid = blockIdx.x;
  const int b = bid >> 6;
  const int ty = (bid >> 3) & 7;
  const int tx = bid & 7;
  const int t = threadIdx.x;
  const int lane = t & 63;

  __shared__ float A_sh[64], B_sh[64];
  __shared__ float red[1024];
  __shared__ __align__(16) float ft_l[100][68];   // 27.2 KB (pad 68)
  __shared__ __align__(16) float G_l[100][68];    // 27.2 KB (pad 68)

  // Wc column + bc preload (lane = o)
  float wcreg[64];
  #pragma unroll
  for (int c = 0; c < 64; ++c) wcreg[c] = WS[WC_OFF + c * 64 + lane];
  const float bcv = WS[BC_OFF + lane];

  // ---- phase 0: stats -> A,B
  {
    const int c = t & 63, qq = t >> 6;
    const float* p = WS + P_OFF + (((size_t)b * 64 + qq * 8) * 64 + c) * 2;
    float S1 = 0.f, S2 = 0.f;
    #pragma unroll
    for (int rr = 0; rr < 8; ++rr) { S1 += p[rr * 128]; S2 += p[rr * 128 + 1]; }
    red[t] = S1; red[512 + t] = S2;
  }
  __syncthreads();
  if (t < 64) {
    float S1 = 0.f, S2 = 0.f;
    #pragma unroll
    for (int qq = 0; qq < 8; ++qq) { S1 += red[qq * 64 + t]; S2 += red[512 + qq * 64 + t]; }
    const float mu = S1 * (1.f / 4096.f);
    const float var = S2 * (1.f / 4096.f) - mu * mu;
    const float dm = WS[DM_OFF + b * 64 + t];
    const float rstd = rsqrtf(dm * dm * var + 1e-5f);
    const float A = dm * rstd * scale2[b * 64 + t];
    A_sh[t] = A;
    B_sh[t] = -mu * A + shiftp[b * 64 + t] + act_b[t];
  }
  __syncthreads();

  // ---- phase 1: stage 10x10 cell patch, affine + leaky, channel-contiguous
  const int cy_base = ty * 8 - 1, cx_base = tx * 8 - 1;
  {
    const float4* A4 = (const float4*)A_sh;
    const float4* B4 = (const float4*)B_sh;
    const float* yb = WS + Y_OFF + ((size_t)b << 18);
    for (int f = t; f < 1600; f += 512) {
      const int cell = f >> 4, cq = f & 15;
      const int li = cell / 10, lj = cell - li * 10;
      const int ciy = cy_base + li, cix = cx_base + lj;
      if (ciy >= 0 && ciy < 64 && cix >= 0 && cix < 64) {
        const float4 y4 = *(const float4*)(yb + (((ciy << 6) + cix) << 6) + cq * 4);
        const float4 Av = A4[cq], Bv = B4[cq];
        float4 fv;
        float u;
        u = y4.x * Av.x + Bv.x; fv.x = (u > 0.f ? u : 0.2f * u) * SQRT2F;
        u = y4.y * Av.y + Bv.y; fv.y = (u > 0.f ? u : 0.2f * u) * SQRT2F;
        u = y4.z * Av.z + Bv.z; fv.z = (u > 0.f ? u : 0.2f * u) * SQRT2F;
        u = y4.w * Av.w + Bv.w; fv.w = (u > 0.f ? u : 0.2f * u) * SQRT2F;
        *(float4*)&ft_l[cell][cq * 4] = fv;
      }
    }
  }
  __syncthreads();

  // ---- phase 2: G_l[cell][o] = bc[o] + sum_c ft_l[cell][c] * Wc[c][o]
  {
    const int w = t >> 6;
    #pragma unroll
    for (int p = 0; p < 4; ++p) {
      const int cb = p * 32 + w * 4;
      if (cb < 100) {
        #pragma unroll
        for (int i2 = 0; i2 < 4; ++i2) {
          float a = bcv;
          const float* fr = ft_l[cb + i2];
          #pragma unroll
          for (int c = 0; c < 64; c += 4) {
            const float4 fv = *(const float4*)&fr[c];
            a = fmaf(fv.x, wcreg[c], a);
            a = fmaf(fv.y, wcreg[c + 1], a);
            a = fmaf(fv.z, wcreg[c + 2], a);
            a = fmaf(fv.w, wcreg[c + 3], a);
          }
          G_l[cb + i2][lane] = a;
        }
      }
    }
  }

  // rel-term Wc rows 64,65 (per quad-sub channel range)
  const int sub = t & 3, chb = sub * 16;
  float4 wa[4], wb[4];
  #pragma unroll
  for (int k = 0; k < 4; ++k) {
    wa[k] = *(const float4*)(WS + WC_OFF + 64 * 64 + chb + k * 4);
    wb[k] = *(const float4*)(WS + WC_OFF + 65 * 64 + chb + k * 4);
  }
  __syncthreads();

  // ---- phase 3: 1024 queries, 4 threads/query, 8 passes
  const float lo = -1.f + 1e-6f, hi = 1.f - 1e-6f;
  #pragma unroll 1
  for (int pass = 0; pass < 8; ++pass) {
    const int qi = pass * 128 + (t >> 2);
    const int oy = (ty << 5) + (qi >> 5), ox = (tx << 5) + (qi & 31);

    const float cy0 = -1.f + (2.f * oy + 1.f) * (1.f / 256.f);
    const float cx0 = -1.f + (2.f * ox + 1.f) * (1.f / 256.f);

    int lcell[4];
    float area[4], rely[4], relx[4];
    int j = 0;
    #pragma unroll
    for (int vx = -1; vx <= 1; vx += 2) {
      #pragma unroll
      for (int vy = -1; vy <= 1; vy += 2) {
        float cy = cy0 + (float)vx * (1.f / 64.f) + 1e-6f;
        cy = fminf(fmaxf(cy, lo), hi);
        float cx = cx0 + (float)vy * (1.f / 64.f) + 1e-6f;
        cx = fminf(fmaxf(cx, lo), hi);
        const float fy = floorf((cy + 1.f) * 32.f);
        const float fx = floorf((cx + 1.f) * 32.f);
        const int iy = (int)fminf(fmaxf(fy, 0.f), 63.f);
        const int ix = (int)fminf(fmaxf(fx, 0.f), 63.f);
        const float qy = -1.f + (2.f * iy + 1.f) * (1.f / 64.f);
        const float qx = -1.f + (2.f * ix + 1.f) * (1.f / 64.f);
        const float ry_ = (cy0 - qy) * 64.f;
        const float rx_ = (cx0 - qx) * 64.f;
        lcell[j] = (iy - cy_base) * 10 + (ix - cx_base);
        rely[j] = ry_; relx[j] = rx_;
        area[j] = fabsf(ry_ * rx_) + 1e-9f;
        ++j;
      }
    }
    const float tot = area[0] + area[1] + area[2] + area[3];
    float wgt[4];
    #pragma unroll
    for (int k = 0; k < 4; ++k) wgt[k] = area[3 - k] / tot;   // diagonal swap
    const float swy = wgt[0] * rely[0] + wgt[1] * rely[1] + wgt[2] * rely[2] + wgt[3] * rely[3];
    const float swx = wgt[0] * relx[0] + wgt[1] * relx[1] + wgt[2] * relx[2] + wgt[3] * relx[3];

    float4 r[4];
    #pragma unroll
    for (int k = 0; k < 4; ++k) {
      r[k].x = swy * wa[k].x + swx * wb[k].x;
      r[k].y = swy * wa[k].y + swx * wb[k].y;
      r[k].z = swy * wa[k].z + swx * wb[k].z;
      r[k].w = swy * wa[k].w + swx * wb[k].w;
    }
    #pragma unroll
    for (int jj = 0; jj < 4; ++jj) {
      const float4* gp = (const float4*)&G_l[lcell[jj]][chb];
      const float wv = wgt[jj];
      #pragma unroll
      for (int k = 0; k < 4; ++k) {
        const float4 gv = gp[k];
        r[k].x += wv * gv.x; r[k].y += wv * gv.y;
        r[k].z += wv * gv.z; r[k].w += wv * gv.w;
      }
    }
    const size_t gq = ((size_t)b << 16) + (oy << 8) + ox;
    float4* op = (float4*)(out + (gq << 6) + chb);
    #pragma unroll
    for (int k = 0; k < 4; ++k) op[k] = r[k];
  }
}

// ---------------------------------------------------------------------------
extern "C" void kernel_launch(void* const* d_in, const int* in_sizes, int n_in,
                              void* d_out, int out_size, void* d_ws, size_t ws_size,
                              hipStream_t stream) {
  (void)in_sizes; (void)n_in; (void)out_size; (void)d_ws; (void)ws_size;
  const float* x      = (const float*)d_in[0];
  const float* scale1 = (const float*)d_in[1];
  const float* scale2 = (const float*)d_in[2];
  const float* shiftp = (const float*)d_in[3];
  const float* mod_w  = (const float*)d_in[4];
  const float* mod_b  = (const float*)d_in[5];
  const float* conv_w = (const float*)d_in[6];
  const float* act_b  = (const float*)d_in[7];
  const float* w1     = (const float*)d_in[8];
  const float* b1     = (const float*)d_in[9];
  const float* w2     = (const float*)d_in[10];
  const float* b2     = (const float*)d_in[11];
  float* out = (float*)d_out;

  hipLaunchKernelGGL(fused1_kernel, dim3(277), dim3(256), 0, stream,
                     x, scale1, mod_w, mod_b, conv_w, b1, w2, b2, w1);
  hipLaunchKernelGGL(gout_kernel, dim3(256), dim3(512), 0, stream,
                     scale2, shiftp, act_b, out);
}